// Round 2
// baseline (2808.513 us; speedup 1.0000x reference)
//
#include <hip/hip_runtime.h>

#define B_   32
#define L_   11
#define N_   577
#define C_   768
#define H_   12
#define HD_  64
#define M_   (B_ * N_)      // 18464
#define NP_  608            // padded key count (19*32)
#define QT_  16             // q rows per attention block
#define NQT_ 37             // ceil(577/16)
#define MCH_ 4616           // M_/4 rows per MLP chunk

typedef unsigned int uint32;

typedef short bf16x8 __attribute__((ext_vector_type(8)));
typedef float f32x4  __attribute__((ext_vector_type(4)));

__device__ __forceinline__ unsigned short f2bf(float f) {
    union { float f; uint32 u; } c; c.f = f;
    uint32 u = c.u;
    uint32 r = (u + 0x7FFFu + ((u >> 16) & 1u)) >> 16;
    return (unsigned short)r;
}
__device__ __forceinline__ float bf2f(unsigned short u) {
    union { uint32 u; float f; } c; c.u = ((uint32)u) << 16;
    return c.f;
}
__device__ __forceinline__ float ldval(const float* p, size_t i) { return p[i]; }
__device__ __forceinline__ float ldval(const unsigned short* p, size_t i) { return bf2f(p[i]); }

__device__ __forceinline__ bf16x8 ld_frag(const unsigned short* p) {
    union { uint4 u; bf16x8 v; } c;
    c.u = *reinterpret_cast<const uint4*>(p);
    return c.v;
}

// ---------------- cast fp32 -> bf16 ----------------
__global__ __launch_bounds__(256) void cast_kernel(const float* __restrict__ src,
                                                   unsigned short* __restrict__ dst, int n) {
    int i = blockIdx.x * 256 + threadIdx.x;
    if (i < n) dst[i] = f2bf(src[i]);
}

// ---------------- prune: token mask ----------------
__global__ __launch_bounds__(256) void prune_kernel(const float* __restrict__ scores,
                                                    float* __restrict__ maskf,
                                                    float* __restrict__ cnt) {
    int b = blockIdx.x, tid = threadIdx.x;
    int lane = tid & 63, wave = tid >> 6;
    __shared__ float ps[576];
    __shared__ float red[4];
    for (int j = tid; j < 576; j += 256) ps[j] = 0.f;
    __syncthreads();
    for (int l = 0; l < L_; ++l) {
        const float* row = scores + ((size_t)b * L_ + l) * N_ + 1;
        float mx = -3.4e38f;
        for (int j = tid; j < 576; j += 256) mx = fmaxf(mx, row[j]);
        for (int off = 32; off; off >>= 1) mx = fmaxf(mx, __shfl_xor(mx, off));
        if (lane == 0) red[wave] = mx;
        __syncthreads();
        mx = fmaxf(fmaxf(red[0], red[1]), fmaxf(red[2], red[3]));
        __syncthreads();
        float s = 0.f;
        for (int j = tid; j < 576; j += 256) s += expf(row[j] - mx);
        for (int off = 32; off; off >>= 1) s += __shfl_xor(s, off);
        if (lane == 0) red[wave] = s;
        __syncthreads();
        s = red[0] + red[1] + red[2] + red[3];
        float inv = 1.f / s;
        for (int j = tid; j < 576; j += 256) ps[j] += expf(row[j] - mx) * inv;
        __syncthreads();
    }
    for (int j = tid; j < 576; j += 256) ps[j] = ps[j] / 11.0f;
    __syncthreads();
    int kept = 0;
    for (int i = tid; i < 576; i += 256) {
        float vi = ps[i];
        float s = 0.f;
        for (int j = 0; j < 576; ++j) {
            float vj = ps[j];
            if (vj < vi || (vj == vi && j <= i)) s += vj;
        }
        int k = (s > 0.5f) ? 1 : 0;
        maskf[b * N_ + 1 + i] = (float)k;
        kept += k;
    }
    __syncthreads();
    for (int off = 32; off; off >>= 1) kept += __shfl_xor(kept, off);
    if (lane == 0) red[wave] = (float)kept;
    __syncthreads();
    if (tid == 0) {
        cnt[b] = red[0] + red[1] + red[2] + red[3] + 1.f;  // +CLS
        maskf[b * N_] = 1.f;
    }
}

// ---------------- layer norm (row-wise): optional bf16 out, optional stats ----------------
template<typename T>
__global__ __launch_bounds__(256) void ln_kernel(const T* __restrict__ x,
                                                 const float* __restrict__ g,
                                                 const float* __restrict__ bta,
                                                 unsigned short* __restrict__ dst_bf,
                                                 float* __restrict__ mu_out,
                                                 float* __restrict__ rs_out) {
    int row = blockIdx.x, tid = threadIdx.x;
    int lane = tid & 63, wave = tid >> 6;
    const T* xr = x + (size_t)row * C_;
    __shared__ float s1[4], s2[4];
    float s = 0.f, sq = 0.f;
    for (int c = tid; c < C_; c += 256) { float v = ldval(xr, c); s += v; sq += v * v; }
    for (int off = 32; off; off >>= 1) { s += __shfl_xor(s, off); sq += __shfl_xor(sq, off); }
    if (lane == 0) { s1[wave] = s; s2[wave] = sq; }
    __syncthreads();
    float ts = s1[0] + s1[1] + s1[2] + s1[3];
    float tq = s2[0] + s2[1] + s2[2] + s2[3];
    float mean = ts / (float)C_;
    float var = tq / (float)C_ - mean * mean;
    float rs = rsqrtf(var + 1e-6f);
    if (mu_out && tid == 0) { mu_out[row] = mean; rs_out[row] = rs; }
    if (dst_bf) {
        for (int c = tid; c < C_; c += 256) {
            float v = (ldval(xr, c) - mean) * rs * g[c] + bta[c];
            dst_bf[(size_t)row * C_ + c] = f2bf(v);
        }
    }
}

// ---------------- GEMM: C[m,n] = sum_k A[m,k]*B[n,k]  (both K-contiguous bf16) ----------------
// MODE 0: qkv split store (q scaled, v transposed)
// MODE 1: +bias +resid(f32) -> bf16 out
// MODE 2: +bias, exact gelu -> bf16 out
// MODE 3: +bias +resid(bf16) -> bf16 out
template<int MODE>
__global__ __launch_bounds__(256) void gemm_kernel(const unsigned short* __restrict__ A,
                                                   const unsigned short* __restrict__ Bm,
                                                   const float* __restrict__ bias,
                                                   const float* __restrict__ residf,
                                                   const unsigned short* __restrict__ residb,
                                                   unsigned short* __restrict__ outb,
                                                   unsigned short* __restrict__ qd,
                                                   unsigned short* __restrict__ kd,
                                                   unsigned short* __restrict__ vd,
                                                   int M, int N, int K) {
    int bid = blockIdx.x;
    int NT = N >> 6;
    int mt = bid / NT, nt = bid % NT;
    int lane = threadIdx.x & 63, wave = threadIdx.x >> 6;
    int m0 = mt * 64 + (wave & 1) * 32;
    int n0 = nt * 64 + (wave >> 1) * 32;
    int ml = lane & 15, kq = (lane >> 4) * 8;
    const unsigned short* a0 = A + (size_t)min(m0 + ml, M - 1) * K + kq;
    const unsigned short* a1 = A + (size_t)min(m0 + 16 + ml, M - 1) * K + kq;
    const unsigned short* b0 = Bm + (size_t)(n0 + ml) * K + kq;
    const unsigned short* b1 = Bm + (size_t)(n0 + 16 + ml) * K + kq;
    f32x4 acc[2][2] = {};
    for (int k = 0; k < K; k += 32) {
        bf16x8 af0 = ld_frag(a0 + k);
        bf16x8 af1 = ld_frag(a1 + k);
        bf16x8 bf0 = ld_frag(b0 + k);
        bf16x8 bf1 = ld_frag(b1 + k);
        acc[0][0] = __builtin_amdgcn_mfma_f32_16x16x32_bf16(af0, bf0, acc[0][0], 0, 0, 0);
        acc[0][1] = __builtin_amdgcn_mfma_f32_16x16x32_bf16(af0, bf1, acc[0][1], 0, 0, 0);
        acc[1][0] = __builtin_amdgcn_mfma_f32_16x16x32_bf16(af1, bf0, acc[1][0], 0, 0, 0);
        acc[1][1] = __builtin_amdgcn_mfma_f32_16x16x32_bf16(af1, bf1, acc[1][1], 0, 0, 0);
    }
    int rbase = (lane >> 4) * 4;
#pragma unroll
    for (int i = 0; i < 2; ++i)
#pragma unroll
    for (int j = 0; j < 2; ++j)
#pragma unroll
    for (int r = 0; r < 4; ++r) {
        int row = m0 + 16 * i + rbase + r;
        if (row >= M) continue;
        int col = n0 + 16 * j + ml;
        float v = acc[i][j][r] + bias[col];
        if (MODE == 0) {
            int b = row / N_, t = row - b * N_;
            int f = col;
            if (f < 768) {
                qd[((size_t)(b * H_ + (f >> 6)) * N_ + t) * HD_ + (f & 63)] = f2bf(v * 0.125f);
            } else if (f < 1536) {
                f -= 768;
                kd[((size_t)(b * H_ + (f >> 6)) * N_ + t) * HD_ + (f & 63)] = f2bf(v);
            } else {
                f -= 1536;
                vd[((size_t)(b * H_ + (f >> 6)) * HD_ + (f & 63)) * NP_ + t] = f2bf(v);
            }
        } else if (MODE == 1) {
            outb[(size_t)row * N + col] = f2bf(v + residf[(size_t)row * N + col]);
        } else if (MODE == 2) {
            float gl = 0.5f * v * (1.f + erff(v * 0.70710678118654752f));
            outb[(size_t)row * N + col] = f2bf(gl);
        } else {
            outb[(size_t)row * N + col] = f2bf(v + bf2f(residb[(size_t)row * N + col]));
        }
    }
}

// ---------------- fused masked attention (per 16-row q tile) ----------------
__global__ __launch_bounds__(256) void attn_kernel(const unsigned short* __restrict__ qb,
                                                   const unsigned short* __restrict__ kb,
                                                   const unsigned short* __restrict__ vt,
                                                   const float* __restrict__ maskf,
                                                   unsigned short* __restrict__ ybf) {
    int bid = blockIdx.x;
    int qt = bid % NQT_;
    int bh = bid / NQT_;
    int h = bh % H_, b = bh / H_;
    int q0 = qt * QT_;
    int tid = threadIdx.x, lane = tid & 63, wave = tid >> 6;
    int ml = lane & 15, kq = (lane >> 4) * 8;
    __shared__ __align__(16) float S[QT_][612];
    __shared__ __align__(16) unsigned short P[QT_][NP_];
    __shared__ float mrow[QT_];
    if (tid < QT_) {
        int t = q0 + tid;
        mrow[tid] = (t < N_) ? maskf[b * N_ + t] : 0.f;
    }
    __syncthreads();
    const unsigned short* qbase = qb + (size_t)(b * H_ + h) * N_ * HD_;
    const unsigned short* kbase = kb + (size_t)(b * H_ + h) * N_ * HD_;
    int qrow = min(q0 + ml, N_ - 1);
    bf16x8 aq0 = ld_frag(qbase + (size_t)qrow * HD_ + kq);
    bf16x8 aq1 = ld_frag(qbase + (size_t)qrow * HD_ + kq + 32);
    for (int nt = wave; nt < NP_ / 16; nt += 4) {
        int krow = min(nt * 16 + ml, N_ - 1);
        bf16x8 bk0 = ld_frag(kbase + (size_t)krow * HD_ + kq);
        bf16x8 bk1 = ld_frag(kbase + (size_t)krow * HD_ + kq + 32);
        f32x4 acc = {0.f, 0.f, 0.f, 0.f};
        acc = __builtin_amdgcn_mfma_f32_16x16x32_bf16(aq0, bk0, acc, 0, 0, 0);
        acc = __builtin_amdgcn_mfma_f32_16x16x32_bf16(aq1, bk1, acc, 0, 0, 0);
        int col = nt * 16 + ml;
        float mk = (col < N_) ? maskf[b * N_ + col] : 0.f;
#pragma unroll
        for (int r = 0; r < 4; ++r) {
            int rr = (lane >> 4) * 4 + r;
            float pm = mrow[rr] * mk;
            S[rr][col] = (pm > 0.f) ? acc[r] : -1e9f;
        }
    }
    __syncthreads();
    for (int r = wave * 4; r < wave * 4 + 4; ++r) {
        float mx = -3.4e38f;
        for (int c = lane; c < NP_; c += 64) mx = fmaxf(mx, S[r][c]);
        for (int off = 32; off; off >>= 1) mx = fmaxf(mx, __shfl_xor(mx, off));
        float sum = 0.f;
        float vals[10];
        int idx = 0;
        for (int c = lane; c < NP_; c += 64) { float e = __expf(S[r][c] - mx); vals[idx++] = e; sum += e; }
        for (int off = 32; off; off >>= 1) sum += __shfl_xor(sum, off);
        float inv = mrow[r] / sum;
        idx = 0;
        for (int c = lane; c < NP_; c += 64) P[r][c] = f2bf(vals[idx++] * inv);
    }
    __syncthreads();
    const unsigned short* vrow = vt + ((size_t)(b * H_ + h) * HD_ + wave * 16 + ml) * NP_ + kq;
    const unsigned short* prow = &P[ml][kq];
    f32x4 acc = {0.f, 0.f, 0.f, 0.f};
    for (int ks = 0; ks < NP_; ks += 32) {
        bf16x8 pa = ld_frag(prow + ks);
        bf16x8 vb = ld_frag(vrow + ks);
        acc = __builtin_amdgcn_mfma_f32_16x16x32_bf16(pa, vb, acc, 0, 0, 0);
    }
#pragma unroll
    for (int r = 0; r < 4; ++r) {
        int rr = (lane >> 4) * 4 + r;
        int t = q0 + rr;
        if (t < N_)
            ybf[((size_t)(b * N_ + t)) * C_ + h * HD_ + wave * 16 + ml] = f2bf(acc[r]);
    }
}

// ---------------- masked pooled raw sums of bbn-normalized x2 ----------------
__global__ __launch_bounds__(256) void pool_kernel(const unsigned short* __restrict__ x2,
                                                   const float* __restrict__ mu,
                                                   const float* __restrict__ rs,
                                                   const float* __restrict__ maskf,
                                                   float* __restrict__ praw) {
    int c = blockIdx.x * 256 + threadIdx.x;   // 3 blocks of 256 -> 768
    int tchunk = blockIdx.y;                  // 8 chunks of 73
    int b = blockIdx.z;
    int t0 = tchunk * 73, t1 = min(t0 + 73, N_);
    float s = 0.f;
    for (int t = t0; t < t1; ++t) {
        int row = b * N_ + t;
        float m = maskf[row];
        if (m > 0.f) s += (bf2f(x2[(size_t)row * C_ + c]) - mu[row]) * rs[row];
    }
    atomicAdd(&praw[b * C_ + c], s);
}

// ---------------- finish: bbn affine + /cnt, then final LN -> out ----------------
__global__ __launch_bounds__(256) void final_kernel(const float* __restrict__ praw,
                                                    const float* __restrict__ cnt,
                                                    const float* __restrict__ bg,
                                                    const float* __restrict__ bb,
                                                    const float* __restrict__ og,
                                                    const float* __restrict__ ob,
                                                    float* __restrict__ out) {
    int b = blockIdx.x, tid = threadIdx.x;
    int lane = tid & 63, wave = tid >> 6;
    __shared__ float u[C_];
    __shared__ float r1[4], r2[4];
    float inv = 1.f / cnt[b];
    float s = 0.f, sq = 0.f;
    for (int c = tid; c < C_; c += 256) {
        float v = bg[c] * praw[b * C_ + c] * inv + bb[c];
        u[c] = v; s += v; sq += v * v;
    }
    for (int off = 32; off; off >>= 1) { s += __shfl_xor(s, off); sq += __shfl_xor(sq, off); }
    if (lane == 0) { r1[wave] = s; r2[wave] = sq; }
    __syncthreads();
    float ts = r1[0] + r1[1] + r1[2] + r1[3];
    float tq = r2[0] + r2[1] + r2[2] + r2[3];
    float mean = ts / (float)C_;
    float var = tq / (float)C_ - mean * mean;
    float rstd = rsqrtf(var + 1e-6f);
    for (int c = tid; c < C_; c += 256)
        out[b * C_ + c] = (u[c] - mean) * rstd * og[c] + ob[c];
}

extern "C" void kernel_launch(void* const* d_in, const int* in_sizes, int n_in,
                              void* d_out, int out_size, void* d_ws, size_t ws_size,
                              hipStream_t stream) {
    const float* last_x  = (const float*)d_in[0];
    const float* scores  = (const float*)d_in[1];
    const float* n1g     = (const float*)d_in[2];
    const float* n1b     = (const float*)d_in[3];
    const float* qkv_w   = (const float*)d_in[4];
    const float* qkv_b   = (const float*)d_in[5];
    const float* proj_w  = (const float*)d_in[6];
    const float* proj_b  = (const float*)d_in[7];
    const float* n2g     = (const float*)d_in[8];
    const float* n2b     = (const float*)d_in[9];
    const float* fc1_w   = (const float*)d_in[10];
    const float* fc1_b   = (const float*)d_in[11];
    const float* fc2_w   = (const float*)d_in[12];
    const float* fc2_b   = (const float*)d_in[13];
    const float* bbn_g   = (const float*)d_in[14];
    const float* bbn_b   = (const float*)d_in[15];
    const float* out_g   = (const float*)d_in[16];
    const float* out_b   = (const float*)d_in[17];
    float* out = (float*)d_out;

    // ---- workspace layout: 129.5 MB peak with aliasing ----
    char* w = (char*)d_ws;
    size_t off = 0;
    auto alloc = [&](size_t bytes) -> char* {
        off = (off + 255) & ~(size_t)255;
        char* p = w + off;
        off += bytes;
        return p;
    };
    unsigned short* wq = (unsigned short*)alloc((size_t)2304 * 768 * 2);
    unsigned short* wp = (unsigned short*)alloc((size_t)768 * 768 * 2);
    unsigned short* w1 = (unsigned short*)alloc((size_t)3072 * 768 * 2);
    unsigned short* w2 = (unsigned short*)alloc((size_t)768 * 3072 * 2);
    float* maskf = (float*)alloc((size_t)M_ * 4);
    float* cnt   = (float*)alloc(32 * 4);
    float* mu    = (float*)alloc((size_t)M_ * 4);
    float* rs    = (float*)alloc((size_t)M_ * 4);
    float* praw  = (float*)alloc((size_t)B_ * C_ * 4);
    unsigned short* h_bf = (unsigned short*)alloc((size_t)M_ * C_ * 2);          // h -> y -> act_chunk
    unsigned short* q_bf = (unsigned short*)alloc((size_t)B_ * H_ * N_ * HD_ * 2); // q -> m (LN2 out)
    unsigned short* k_bf = (unsigned short*)alloc((size_t)B_ * H_ * N_ * HD_ * 2); // k -> x2 (bf16)
    unsigned short* vt   = (unsigned short*)alloc((size_t)B_ * H_ * HD_ * NP_ * 2); // vt -> x1 (bf16)
    unsigned short* y_bf = h_bf;    // attention output overwrites h (dead after QKV)
    unsigned short* m_bf = q_bf;    // LN2 out overwrites q (dead after attn)
    unsigned short* x1   = vt;      // proj+resid out overwrites vt (dead after attn); 28.36<=29.88MB
    unsigned short* x2   = k_bf;    // fc2+resid out overwrites k (dead after attn); exact fit
    unsigned short* act  = h_bf;    // fc1 chunk out overwrites y (dead after proj); exact fit

    // 1. cast weights to bf16
    cast_kernel<<<(2304 * 768 + 255) / 256, 256, 0, stream>>>(qkv_w, wq, 2304 * 768);
    cast_kernel<<<(768 * 768 + 255) / 256, 256, 0, stream>>>(proj_w, wp, 768 * 768);
    cast_kernel<<<(3072 * 768 + 255) / 256, 256, 0, stream>>>(fc1_w, w1, 3072 * 768);
    cast_kernel<<<(768 * 3072 + 255) / 256, 256, 0, stream>>>(fc2_w, w2, 768 * 3072);
    // 2. prune mask
    prune_kernel<<<B_, 256, 0, stream>>>(scores, maskf, cnt);
    // 3. LN1 -> h (bf16)
    ln_kernel<float><<<M_, 256, 0, stream>>>(last_x, n1g, n1b, h_bf, nullptr, nullptr);
    // 4. QKV gemm, split store
    gemm_kernel<0><<<((M_ + 63) / 64) * (2304 / 64), 256, 0, stream>>>(
        h_bf, wq, qkv_b, nullptr, nullptr, nullptr, q_bf, k_bf, vt, M_, 2304, C_);
    // 5. masked attention -> y (= h_bf region)
    attn_kernel<<<B_ * H_ * NQT_, 256, 0, stream>>>(q_bf, k_bf, vt, maskf, y_bf);
    // 6. proj gemm + residual(f32 last_x) -> x1 (bf16, vt region)
    gemm_kernel<1><<<((M_ + 63) / 64) * (768 / 64), 256, 0, stream>>>(
        y_bf, wp, proj_b, last_x, nullptr, x1, nullptr, nullptr, nullptr, M_, C_, C_);
    // 7. LN2 -> m (bf16, q region)
    ln_kernel<unsigned short><<<M_, 256, 0, stream>>>(x1, n2g, n2b, m_bf, nullptr, nullptr);
    // 8/9. MLP in 4 row-chunks (act chunk fits h_bf region exactly)
    for (int c = 0; c < 4; ++c) {
        int r0 = c * MCH_;
        gemm_kernel<2><<<((MCH_ + 63) / 64) * (3072 / 64), 256, 0, stream>>>(
            m_bf + (size_t)r0 * C_, w1, fc1_b, nullptr, nullptr, act,
            nullptr, nullptr, nullptr, MCH_, 3072, C_);
        gemm_kernel<3><<<((MCH_ + 63) / 64) * (768 / 64), 256, 0, stream>>>(
            act, w2, fc2_b, nullptr, x1 + (size_t)r0 * C_, x2 + (size_t)r0 * C_,
            nullptr, nullptr, nullptr, MCH_, 768, 3072);
    }
    // 10. bbn LN stats only
    ln_kernel<unsigned short><<<M_, 256, 0, stream>>>(x2, bbn_g, bbn_b, nullptr, mu, rs);
    // 11. masked pooled raw sums
    hipMemsetAsync(praw, 0, (size_t)B_ * C_ * 4, stream);
    dim3 pg(3, 8, B_);
    pool_kernel<<<pg, 256, 0, stream>>>(x2, mu, rs, maskf, praw);
    // 12. bbn affine + /cnt + final LN -> out
    final_kernel<<<B_, 256, 0, stream>>>(praw, cnt, bbn_g, bbn_b, out_g, out_b, out);
    (void)in_sizes; (void)n_in; (void)out_size; (void)ws_size;
}

// Round 3
// 1710.694 us; speedup vs baseline: 1.6417x; 1.6417x over previous
//
#include <hip/hip_runtime.h>

#define B_   32
#define L_   11
#define N_   577
#define C_   768
#define H_   12
#define HD_  64
#define M_   (B_ * N_)      // 18464
#define NP_  608            // padded key count (19*32)
#define QT_  16             // q rows per attention block
#define NQT_ 37             // ceil(577/16)
#define MCH_ 4616           // M_/4 rows per MLP chunk

typedef unsigned int uint32;

typedef short bf16x8 __attribute__((ext_vector_type(8)));
typedef float f32x4  __attribute__((ext_vector_type(4)));

__device__ __forceinline__ unsigned short f2bf(float f) {
    union { float f; uint32 u; } c; c.f = f;
    uint32 u = c.u;
    uint32 r = (u + 0x7FFFu + ((u >> 16) & 1u)) >> 16;
    return (unsigned short)r;
}
__device__ __forceinline__ float bf2f(unsigned short u) {
    union { uint32 u; float f; } c; c.u = ((uint32)u) << 16;
    return c.f;
}
__device__ __forceinline__ float ldval(const float* p, size_t i) { return p[i]; }
__device__ __forceinline__ float ldval(const unsigned short* p, size_t i) { return bf2f(p[i]); }

__device__ __forceinline__ bf16x8 ld_frag(const unsigned short* p) {
    union { uint4 u; bf16x8 v; } c;
    c.u = *reinterpret_cast<const uint4*>(p);
    return c.v;
}

// async global->LDS, 16B per lane; LDS dest is wave-uniform base + lane*16
__device__ __forceinline__ void gload_lds16(const unsigned short* g, unsigned short* l) {
    __builtin_amdgcn_global_load_lds(
        (const __attribute__((address_space(1))) unsigned int*)g,
        (__attribute__((address_space(3))) unsigned int*)l, 16, 0, 0);
}

// ---------------- cast fp32 -> bf16 ----------------
__global__ __launch_bounds__(256) void cast_kernel(const float* __restrict__ src,
                                                   unsigned short* __restrict__ dst, int n) {
    int i = blockIdx.x * 256 + threadIdx.x;
    if (i < n) dst[i] = f2bf(src[i]);
}

// ---------------- prune: token mask ----------------
__global__ __launch_bounds__(256) void prune_kernel(const float* __restrict__ scores,
                                                    float* __restrict__ maskf,
                                                    float* __restrict__ cnt) {
    int b = blockIdx.x, tid = threadIdx.x;
    int lane = tid & 63, wave = tid >> 6;
    __shared__ float ps[576];
    __shared__ float red[4];
    for (int j = tid; j < 576; j += 256) ps[j] = 0.f;
    __syncthreads();
    for (int l = 0; l < L_; ++l) {
        const float* row = scores + ((size_t)b * L_ + l) * N_ + 1;
        float mx = -3.4e38f;
        for (int j = tid; j < 576; j += 256) mx = fmaxf(mx, row[j]);
        for (int off = 32; off; off >>= 1) mx = fmaxf(mx, __shfl_xor(mx, off));
        if (lane == 0) red[wave] = mx;
        __syncthreads();
        mx = fmaxf(fmaxf(red[0], red[1]), fmaxf(red[2], red[3]));
        __syncthreads();
        float s = 0.f;
        for (int j = tid; j < 576; j += 256) s += expf(row[j] - mx);
        for (int off = 32; off; off >>= 1) s += __shfl_xor(s, off);
        if (lane == 0) red[wave] = s;
        __syncthreads();
        s = red[0] + red[1] + red[2] + red[3];
        float inv = 1.f / s;
        for (int j = tid; j < 576; j += 256) ps[j] += expf(row[j] - mx) * inv;
        __syncthreads();
    }
    for (int j = tid; j < 576; j += 256) ps[j] = ps[j] / 11.0f;
    __syncthreads();
    int kept = 0;
    for (int i = tid; i < 576; i += 256) {
        float vi = ps[i];
        float s = 0.f;
        for (int j = 0; j < 576; ++j) {
            float vj = ps[j];
            if (vj < vi || (vj == vi && j <= i)) s += vj;
        }
        int k = (s > 0.5f) ? 1 : 0;
        maskf[b * N_ + 1 + i] = (float)k;
        kept += k;
    }
    __syncthreads();
    for (int off = 32; off; off >>= 1) kept += __shfl_xor(kept, off);
    if (lane == 0) red[wave] = (float)kept;
    __syncthreads();
    if (tid == 0) {
        cnt[b] = red[0] + red[1] + red[2] + red[3] + 1.f;  // +CLS
        maskf[b * N_] = 1.f;
    }
}

// ---------------- layer norm (row-wise): optional bf16 out, optional stats ----------------
template<typename T>
__global__ __launch_bounds__(256) void ln_kernel(const T* __restrict__ x,
                                                 const float* __restrict__ g,
                                                 const float* __restrict__ bta,
                                                 unsigned short* __restrict__ dst_bf,
                                                 float* __restrict__ mu_out,
                                                 float* __restrict__ rs_out) {
    int row = blockIdx.x, tid = threadIdx.x;
    int lane = tid & 63, wave = tid >> 6;
    const T* xr = x + (size_t)row * C_;
    __shared__ float s1[4], s2[4];
    float s = 0.f, sq = 0.f;
    for (int c = tid; c < C_; c += 256) { float v = ldval(xr, c); s += v; sq += v * v; }
    for (int off = 32; off; off >>= 1) { s += __shfl_xor(s, off); sq += __shfl_xor(sq, off); }
    if (lane == 0) { s1[wave] = s; s2[wave] = sq; }
    __syncthreads();
    float ts = s1[0] + s1[1] + s1[2] + s1[3];
    float tq = s2[0] + s2[1] + s2[2] + s2[3];
    float mean = ts / (float)C_;
    float var = tq / (float)C_ - mean * mean;
    float rs = rsqrtf(var + 1e-6f);
    if (mu_out && tid == 0) { mu_out[row] = mean; rs_out[row] = rs; }
    if (dst_bf) {
        for (int c = tid; c < C_; c += 256) {
            float v = (ldval(xr, c) - mean) * rs * g[c] + bta[c];
            dst_bf[(size_t)row * C_ + c] = f2bf(v);
        }
    }
}

// ---------------- GEMM (m97 structure): C[m,n] = sum_k A[m,k]*B[n,k], bf16 in ----------------
// TILE = MI*32 square tile; 4 waves, each (MI*16)x(MI*16) via MI x MI 16x16x32 frags.
// LDS staged via global_load_lds width=16; BK=32.
// MODE 0: qkv split store (q scaled, v transposed)
// MODE 1: +bias +resid(f32) -> bf16 out
// MODE 2: +bias, exact gelu -> bf16 out
// MODE 3: +bias +resid(bf16) -> bf16 out
template<int MODE, int MI>
__global__ __launch_bounds__(256) void gemm_kernel(const unsigned short* __restrict__ A,
                                                   const unsigned short* __restrict__ Bm,
                                                   const float* __restrict__ bias,
                                                   const float* __restrict__ residf,
                                                   const unsigned short* __restrict__ residb,
                                                   unsigned short* __restrict__ outb,
                                                   unsigned short* __restrict__ qd,
                                                   unsigned short* __restrict__ kd,
                                                   unsigned short* __restrict__ vd,
                                                   int M, int N, int K) {
    constexpr int TILE = MI * 32;
    __shared__ unsigned short As[TILE * 32];   // row-major, 32 bf16 (64B) per row
    __shared__ unsigned short Bs[TILE * 32];
    int bid = blockIdx.x;
    int NT = N / TILE;
    int mt = bid / NT, nt = bid % NT;
    int m0 = mt * TILE, n0 = nt * TILE;
    int tid = threadIdx.x, lane = tid & 63, wave = tid >> 6;
    int ml = lane & 15, quad = lane >> 4;
    // staging: issue jj covers rows [jj*64, jj*64+64); within: wave w rows w*16+(l>>2), k byte (l&3)*16
    int srow = wave * 16 + (lane >> 2);
    int skc = (lane & 3) * 8;
    const unsigned short* ag[MI / 2 == 0 ? 1 : MI / 2];
    const unsigned short* bg[MI / 2 == 0 ? 1 : MI / 2];
#pragma unroll
    for (int jj = 0; jj < MI / 2; ++jj) {
        ag[jj] = A + (size_t)min(m0 + jj * 64 + srow, M - 1) * K + skc;
        bg[jj] = Bm + (size_t)(n0 + jj * 64 + srow) * K + skc;
    }
    int msub = (wave & 1) * (MI * 16), nsub = (wave >> 1) * (MI * 16);
    f32x4 acc[MI][MI] = {};
    for (int k0 = 0; k0 < K; k0 += 32) {
        __syncthreads();
#pragma unroll
        for (int jj = 0; jj < MI / 2; ++jj) {
            gload_lds16(ag[jj] + k0, As + jj * 2048 + wave * 512);
            gload_lds16(bg[jj] + k0, Bs + jj * 2048 + wave * 512);
        }
        asm volatile("s_waitcnt vmcnt(0)" ::: "memory");
        __syncthreads();
        bf16x8 af[MI], bfm[MI];
#pragma unroll
        for (int i = 0; i < MI; ++i) af[i] = ld_frag(As + (msub + 16 * i + ml) * 32 + quad * 8);
#pragma unroll
        for (int j = 0; j < MI; ++j) bfm[j] = ld_frag(Bs + (nsub + 16 * j + ml) * 32 + quad * 8);
#pragma unroll
        for (int i = 0; i < MI; ++i)
#pragma unroll
            for (int j = 0; j < MI; ++j)
                acc[i][j] = __builtin_amdgcn_mfma_f32_16x16x32_bf16(af[i], bfm[j], acc[i][j], 0, 0, 0);
    }
#pragma unroll
    for (int i = 0; i < MI; ++i)
#pragma unroll
    for (int j = 0; j < MI; ++j)
#pragma unroll
    for (int r = 0; r < 4; ++r) {
        int row = m0 + msub + 16 * i + quad * 4 + r;
        if (row >= M) continue;
        int col = n0 + nsub + 16 * j + ml;
        float v = acc[i][j][r] + bias[col];
        if (MODE == 0) {
            int b = row / N_, t = row - b * N_;
            int f = col;
            if (f < 768) {
                qd[((size_t)(b * H_ + (f >> 6)) * N_ + t) * HD_ + (f & 63)] = f2bf(v * 0.125f);
            } else if (f < 1536) {
                f -= 768;
                kd[((size_t)(b * H_ + (f >> 6)) * N_ + t) * HD_ + (f & 63)] = f2bf(v);
            } else {
                f -= 1536;
                vd[((size_t)(b * H_ + (f >> 6)) * HD_ + (f & 63)) * NP_ + t] = f2bf(v);
            }
        } else if (MODE == 1) {
            outb[(size_t)row * N + col] = f2bf(v + residf[(size_t)row * N + col]);
        } else if (MODE == 2) {
            float gl = 0.5f * v * (1.f + erff(v * 0.70710678118654752f));
            outb[(size_t)row * N + col] = f2bf(gl);
        } else {
            outb[(size_t)row * N + col] = f2bf(v + bf2f(residb[(size_t)row * N + col]));
        }
    }
}

// ---------------- fused masked attention (per 16-row q tile) ----------------
// grid = 14208 = 8 XCD-groups x 48 bh x 37 qt; bh chosen so bh == blockIdx (mod 8)
// keeps one (b,h)'s K/V resident in a single XCD's L2.
__global__ __launch_bounds__(256) void attn_kernel(const unsigned short* __restrict__ qb,
                                                   const unsigned short* __restrict__ kb,
                                                   const unsigned short* __restrict__ vt,
                                                   const float* __restrict__ maskf,
                                                   unsigned short* __restrict__ ybf) {
    int bid = blockIdx.x;
    int xcd = bid & 7, idx = bid >> 3;
    int bh = (idx % 48) * 8 + xcd;
    int qt = idx / 48;
    int h = bh % H_, b = bh / H_;
    int q0 = qt * QT_;
    int tid = threadIdx.x, lane = tid & 63, wave = tid >> 6;
    int ml = lane & 15, quad = lane >> 4, kq = quad * 8;
    __shared__ __align__(16) float S[QT_][612];          // stride 612 f32: phase1 writes 2-way (free)
    __shared__ __align__(16) unsigned short P[QT_][616]; // stride 616 bf16: phase3 b128 reads conflict-free
    __shared__ float mrow[QT_];
    if (tid < QT_) {
        int t = q0 + tid;
        mrow[tid] = (t < N_) ? maskf[b * N_ + t] : 0.f;
    }
    // prefetch all V fragments (independent of everything) — hides HBM latency behind phases 1-2
    const unsigned short* vrow = vt + ((size_t)(b * H_ + h) * HD_ + wave * 16 + ml) * NP_ + kq;
    bf16x8 vf[19];
#pragma unroll
    for (int t = 0; t < 19; ++t) vf[t] = ld_frag(vrow + t * 32);
    __syncthreads();
    // phase 1: S = (q*scale) @ k^T with pair mask
    const unsigned short* qbase = qb + (size_t)(b * H_ + h) * N_ * HD_;
    const unsigned short* kbase = kb + (size_t)(b * H_ + h) * N_ * HD_;
    int qrow = min(q0 + ml, N_ - 1);
    bf16x8 aq0 = ld_frag(qbase + (size_t)qrow * HD_ + kq);
    bf16x8 aq1 = ld_frag(qbase + (size_t)qrow * HD_ + kq + 32);
    for (int nt = wave; nt < NP_ / 16; nt += 4) {
        int krow = min(nt * 16 + ml, N_ - 1);
        bf16x8 bk0 = ld_frag(kbase + (size_t)krow * HD_ + kq);
        bf16x8 bk1 = ld_frag(kbase + (size_t)krow * HD_ + kq + 32);
        f32x4 acc = {0.f, 0.f, 0.f, 0.f};
        acc = __builtin_amdgcn_mfma_f32_16x16x32_bf16(aq0, bk0, acc, 0, 0, 0);
        acc = __builtin_amdgcn_mfma_f32_16x16x32_bf16(aq1, bk1, acc, 0, 0, 0);
        int col = nt * 16 + ml;
        float mk = (col < N_) ? maskf[b * N_ + col] : 0.f;
#pragma unroll
        for (int r = 0; r < 4; ++r) {
            int rr = quad * 4 + r;
            float pm = mrow[rr] * mk;
            S[rr][col] = (pm > 0.f) ? acc[r] : -1e9f;
        }
    }
    __syncthreads();
    // phase 2: row softmax (recompute exp on 2nd pass — no dynamic-index array)
    for (int r = wave * 4; r < wave * 4 + 4; ++r) {
        float mx = -3.4e38f;
        for (int c = lane; c < NP_; c += 64) mx = fmaxf(mx, S[r][c]);
        for (int off = 32; off; off >>= 1) mx = fmaxf(mx, __shfl_xor(mx, off));
        float sum = 0.f;
        for (int c = lane; c < NP_; c += 64) sum += __expf(S[r][c] - mx);
        for (int off = 32; off; off >>= 1) sum += __shfl_xor(sum, off);
        float inv = mrow[r] / sum;
        for (int c = lane; c < NP_; c += 64) P[r][c] = f2bf(__expf(S[r][c] - mx) * inv);
    }
    __syncthreads();
    // phase 3: O = P @ V (V already in registers)
    const unsigned short* prow = &P[ml][0] + kq;
    f32x4 acc = {0.f, 0.f, 0.f, 0.f};
#pragma unroll
    for (int t = 0; t < 19; ++t) {
        bf16x8 pa = ld_frag(prow + t * 32);
        acc = __builtin_amdgcn_mfma_f32_16x16x32_bf16(pa, vf[t], acc, 0, 0, 0);
    }
#pragma unroll
    for (int r = 0; r < 4; ++r) {
        int rr = quad * 4 + r;
        int t = q0 + rr;
        if (t < N_)
            ybf[((size_t)(b * N_ + t)) * C_ + h * HD_ + wave * 16 + ml] = f2bf(acc[r]);
    }
}

// ---------------- masked pooled raw sums of bbn-normalized x2 ----------------
__global__ __launch_bounds__(256) void pool_kernel(const unsigned short* __restrict__ x2,
                                                   const float* __restrict__ mu,
                                                   const float* __restrict__ rs,
                                                   const float* __restrict__ maskf,
                                                   float* __restrict__ praw) {
    int c = blockIdx.x * 256 + threadIdx.x;   // 3 blocks of 256 -> 768
    int tchunk = blockIdx.y;                  // 8 chunks of 73
    int b = blockIdx.z;
    int t0 = tchunk * 73, t1 = min(t0 + 73, N_);
    float s = 0.f;
    for (int t = t0; t < t1; ++t) {
        int row = b * N_ + t;
        float m = maskf[row];
        if (m > 0.f) s += (bf2f(x2[(size_t)row * C_ + c]) - mu[row]) * rs[row];
    }
    atomicAdd(&praw[b * C_ + c], s);
}

// ---------------- finish: bbn affine + /cnt, then final LN -> out ----------------
__global__ __launch_bounds__(256) void final_kernel(const float* __restrict__ praw,
                                                    const float* __restrict__ cnt,
                                                    const float* __restrict__ bg,
                                                    const float* __restrict__ bb,
                                                    const float* __restrict__ og,
                                                    const float* __restrict__ ob,
                                                    float* __restrict__ out) {
    int b = blockIdx.x, tid = threadIdx.x;
    int lane = tid & 63, wave = tid >> 6;
    __shared__ float u[C_];
    __shared__ float r1[4], r2[4];
    float inv = 1.f / cnt[b];
    float s = 0.f, sq = 0.f;
    for (int c = tid; c < C_; c += 256) {
        float v = bg[c] * praw[b * C_ + c] * inv + bb[c];
        u[c] = v; s += v; sq += v * v;
    }
    for (int off = 32; off; off >>= 1) { s += __shfl_xor(s, off); sq += __shfl_xor(sq, off); }
    if (lane == 0) { r1[wave] = s; r2[wave] = sq; }
    __syncthreads();
    float ts = r1[0] + r1[1] + r1[2] + r1[3];
    float tq = r2[0] + r2[1] + r2[2] + r2[3];
    float mean = ts / (float)C_;
    float var = tq / (float)C_ - mean * mean;
    float rstd = rsqrtf(var + 1e-6f);
    for (int c = tid; c < C_; c += 256)
        out[b * C_ + c] = (u[c] - mean) * rstd * og[c] + ob[c];
}

extern "C" void kernel_launch(void* const* d_in, const int* in_sizes, int n_in,
                              void* d_out, int out_size, void* d_ws, size_t ws_size,
                              hipStream_t stream) {
    const float* last_x  = (const float*)d_in[0];
    const float* scores  = (const float*)d_in[1];
    const float* n1g     = (const float*)d_in[2];
    const float* n1b     = (const float*)d_in[3];
    const float* qkv_w   = (const float*)d_in[4];
    const float* qkv_b   = (const float*)d_in[5];
    const float* proj_w  = (const float*)d_in[6];
    const float* proj_b  = (const float*)d_in[7];
    const float* n2g     = (const float*)d_in[8];
    const float* n2b     = (const float*)d_in[9];
    const float* fc1_w   = (const float*)d_in[10];
    const float* fc1_b   = (const float*)d_in[11];
    const float* fc2_w   = (const float*)d_in[12];
    const float* fc2_b   = (const float*)d_in[13];
    const float* bbn_g   = (const float*)d_in[14];
    const float* bbn_b   = (const float*)d_in[15];
    const float* out_g   = (const float*)d_in[16];
    const float* out_b   = (const float*)d_in[17];
    float* out = (float*)d_out;

    // ---- workspace layout: ~129.5 MB peak with aliasing ----
    char* w = (char*)d_ws;
    size_t off = 0;
    auto alloc = [&](size_t bytes) -> char* {
        off = (off + 255) & ~(size_t)255;
        char* p = w + off;
        off += bytes;
        return p;
    };
    unsigned short* wq = (unsigned short*)alloc((size_t)2304 * 768 * 2);
    unsigned short* wp = (unsigned short*)alloc((size_t)768 * 768 * 2);
    unsigned short* w1 = (unsigned short*)alloc((size_t)3072 * 768 * 2);
    unsigned short* w2 = (unsigned short*)alloc((size_t)768 * 3072 * 2);
    float* maskf = (float*)alloc((size_t)M_ * 4);
    float* cnt   = (float*)alloc(32 * 4);
    float* mu    = (float*)alloc((size_t)M_ * 4);
    float* rs    = (float*)alloc((size_t)M_ * 4);
    float* praw  = (float*)alloc((size_t)B_ * C_ * 4);
    unsigned short* h_bf = (unsigned short*)alloc((size_t)M_ * C_ * 2);           // h -> y -> act_chunk
    unsigned short* q_bf = (unsigned short*)alloc((size_t)B_ * H_ * N_ * HD_ * 2); // q -> m (LN2 out)
    unsigned short* k_bf = (unsigned short*)alloc((size_t)B_ * H_ * N_ * HD_ * 2); // k -> x2 (bf16)
    unsigned short* vt   = (unsigned short*)alloc((size_t)B_ * H_ * HD_ * NP_ * 2); // vt -> x1 (bf16)
    unsigned short* y_bf = h_bf;    // attention output overwrites h (dead after QKV)
    unsigned short* m_bf = q_bf;    // LN2 out overwrites q (dead after attn)
    unsigned short* x1   = vt;      // proj+resid out overwrites vt (dead after attn)
    unsigned short* x2   = k_bf;    // fc2+resid out overwrites k (dead after attn)
    unsigned short* act  = h_bf;    // fc1 chunk out overwrites y (dead after proj)

    // 1. cast weights to bf16
    cast_kernel<<<(2304 * 768 + 255) / 256, 256, 0, stream>>>(qkv_w, wq, 2304 * 768);
    cast_kernel<<<(768 * 768 + 255) / 256, 256, 0, stream>>>(proj_w, wp, 768 * 768);
    cast_kernel<<<(3072 * 768 + 255) / 256, 256, 0, stream>>>(fc1_w, w1, 3072 * 768);
    cast_kernel<<<(768 * 3072 + 255) / 256, 256, 0, stream>>>(fc2_w, w2, 768 * 3072);
    // 2. prune mask
    prune_kernel<<<B_, 256, 0, stream>>>(scores, maskf, cnt);
    // 3. LN1 -> h (bf16)
    ln_kernel<float><<<M_, 256, 0, stream>>>(last_x, n1g, n1b, h_bf, nullptr, nullptr);
    // 4. QKV gemm (128-tile), split store
    gemm_kernel<0, 4><<<((M_ + 127) / 128) * (2304 / 128), 256, 0, stream>>>(
        h_bf, wq, qkv_b, nullptr, nullptr, nullptr, q_bf, k_bf, vt, M_, 2304, C_);
    // 5. masked attention -> y (= h_bf region)
    attn_kernel<<<B_ * H_ * NQT_, 256, 0, stream>>>(q_bf, k_bf, vt, maskf, y_bf);
    // 6. proj gemm + residual(f32 last_x) -> x1 (bf16, vt region)
    gemm_kernel<1, 4><<<((M_ + 127) / 128) * (768 / 128), 256, 0, stream>>>(
        y_bf, wp, proj_b, last_x, nullptr, x1, nullptr, nullptr, nullptr, M_, C_, C_);
    // 7. LN2 -> m (bf16, q region)
    ln_kernel<unsigned short><<<M_, 256, 0, stream>>>(x1, n2g, n2b, m_bf, nullptr, nullptr);
    // 8/9. MLP in 4 row-chunks; fc2 uses 64-tile (876 blocks vs 222 at 128-tile)
    for (int c = 0; c < 4; ++c) {
        int r0 = c * MCH_;
        gemm_kernel<2, 4><<<((MCH_ + 127) / 128) * (3072 / 128), 256, 0, stream>>>(
            m_bf + (size_t)r0 * C_, w1, fc1_b, nullptr, nullptr, act,
            nullptr, nullptr, nullptr, MCH_, 3072, C_);
        gemm_kernel<3, 2><<<((MCH_ + 63) / 64) * (768 / 64), 256, 0, stream>>>(
            act, w2, fc2_b, nullptr, x1 + (size_t)r0 * C_, x2 + (size_t)r0 * C_,
            nullptr, nullptr, nullptr, MCH_, 768, 3072);
    }
    // 10. bbn LN stats only
    ln_kernel<unsigned short><<<M_, 256, 0, stream>>>(x2, bbn_g, bbn_b, nullptr, mu, rs);
    // 11. masked pooled raw sums
    hipMemsetAsync(praw, 0, (size_t)B_ * C_ * 4, stream);
    dim3 pg(3, 8, B_);
    pool_kernel<<<pg, 256, 0, stream>>>(x2, mu, rs, maskf, praw);
    // 12. bbn affine + /cnt + final LN -> out
    final_kernel<<<B_, 256, 0, stream>>>(praw, cnt, bbn_g, bbn_b, out_g, out_b, out);
    (void)in_sizes; (void)n_in; (void)out_size; (void)ws_size;
}

// Round 4
// 1382.823 us; speedup vs baseline: 2.0310x; 1.2371x over previous
//
#include <hip/hip_runtime.h>

#define B_   32
#define L_   11
#define N_   577
#define C_   768
#define H_   12
#define HD_  64
#define M_   (B_ * N_)      // 18464
#define NP_  608            // padded key count (19*32)
#define QT_  16             // q rows per attention block
#define NQT_ 37             // ceil(577/16)
#define MCH_ 4616           // M_/4 rows per MLP chunk

typedef unsigned int uint32;

typedef short bf16x8 __attribute__((ext_vector_type(8)));
typedef float f32x4  __attribute__((ext_vector_type(4)));

__device__ __forceinline__ unsigned short f2bf(float f) {
    union { float f; uint32 u; } c; c.f = f;
    uint32 u = c.u;
    uint32 r = (u + 0x7FFFu + ((u >> 16) & 1u)) >> 16;
    return (unsigned short)r;
}
__device__ __forceinline__ float bf2f(unsigned short u) {
    union { uint32 u; float f; } c; c.u = ((uint32)u) << 16;
    return c.f;
}
__device__ __forceinline__ float ldval(const float* p, size_t i) { return p[i]; }
__device__ __forceinline__ float ldval(const unsigned short* p, size_t i) { return bf2f(p[i]); }

__device__ __forceinline__ bf16x8 ld_frag(const unsigned short* p) {
    union { uint4 u; bf16x8 v; } c;
    c.u = *reinterpret_cast<const uint4*>(p);
    return c.v;
}

// async global->LDS, 16B per lane; LDS dest is wave-uniform base + lane*16
__device__ __forceinline__ void gload_lds16(const unsigned short* g, unsigned short* l) {
    __builtin_amdgcn_global_load_lds(
        (const __attribute__((address_space(1))) unsigned int*)g,
        (__attribute__((address_space(3))) unsigned int*)l, 16, 0, 0);
}

// ---------------- merged cast fp32 -> bf16 (all 4 weight mats, float4-vectorized) ----------------
__global__ __launch_bounds__(256) void cast4_kernel(const float* __restrict__ qkvw,
                                                    const float* __restrict__ projw,
                                                    const float* __restrict__ fc1w,
                                                    const float* __restrict__ fc2w,
                                                    unsigned short* __restrict__ dq,
                                                    unsigned short* __restrict__ dp,
                                                    unsigned short* __restrict__ d1,
                                                    unsigned short* __restrict__ d2) {
    int i = blockIdx.x * 256 + threadIdx.x;     // vec4 index; total 1,769,472
    const int N0 = 442368, N1 = 147456, N2 = 589824;   // vec4 counts
    const float* s; unsigned short* d; int j;
    if (i < N0)                { s = qkvw; d = dq; j = i; }
    else if (i < N0 + N1)      { s = projw; d = dp; j = i - N0; }
    else if (i < N0 + N1 + N2) { s = fc1w;  d = d1; j = i - N0 - N1; }
    else                       { s = fc2w;  d = d2; j = i - N0 - N1 - N2; }
    float4 v = reinterpret_cast<const float4*>(s)[j];
    union { unsigned short us[4]; uint2 u; } o;
    o.us[0] = f2bf(v.x); o.us[1] = f2bf(v.y); o.us[2] = f2bf(v.z); o.us[3] = f2bf(v.w);
    reinterpret_cast<uint2*>(d)[j] = o.u;
}

// ---------------- prune: token mask ----------------
__global__ __launch_bounds__(256) void prune_kernel(const float* __restrict__ scores,
                                                    float* __restrict__ maskf,
                                                    float* __restrict__ cnt) {
    int b = blockIdx.x, tid = threadIdx.x;
    int lane = tid & 63, wave = tid >> 6;
    __shared__ float ps[576];
    __shared__ float red[4];
    for (int j = tid; j < 576; j += 256) ps[j] = 0.f;
    __syncthreads();
    for (int l = 0; l < L_; ++l) {
        const float* row = scores + ((size_t)b * L_ + l) * N_ + 1;
        float mx = -3.4e38f;
        for (int j = tid; j < 576; j += 256) mx = fmaxf(mx, row[j]);
        for (int off = 32; off; off >>= 1) mx = fmaxf(mx, __shfl_xor(mx, off));
        if (lane == 0) red[wave] = mx;
        __syncthreads();
        mx = fmaxf(fmaxf(red[0], red[1]), fmaxf(red[2], red[3]));
        __syncthreads();
        float s = 0.f;
        for (int j = tid; j < 576; j += 256) s += expf(row[j] - mx);
        for (int off = 32; off; off >>= 1) s += __shfl_xor(s, off);
        if (lane == 0) red[wave] = s;
        __syncthreads();
        s = red[0] + red[1] + red[2] + red[3];
        float inv = 1.f / s;
        for (int j = tid; j < 576; j += 256) ps[j] += expf(row[j] - mx) * inv;
        __syncthreads();
    }
    for (int j = tid; j < 576; j += 256) ps[j] = ps[j] / 11.0f;
    __syncthreads();
    int kept = 0;
    for (int i = tid; i < 576; i += 256) {
        float vi = ps[i];
        float s = 0.f;
        for (int j = 0; j < 576; ++j) {
            float vj = ps[j];
            if (vj < vi || (vj == vi && j <= i)) s += vj;
        }
        int k = (s > 0.5f) ? 1 : 0;
        maskf[b * N_ + 1 + i] = (float)k;
        kept += k;
    }
    __syncthreads();
    for (int off = 32; off; off >>= 1) kept += __shfl_xor(kept, off);
    if (lane == 0) red[wave] = (float)kept;
    __syncthreads();
    if (tid == 0) {
        cnt[b] = red[0] + red[1] + red[2] + red[3] + 1.f;  // +CLS
        maskf[b * N_] = 1.f;
    }
}

// ---------------- layer norm (row-wise): optional bf16 out, optional stats ----------------
template<typename T>
__global__ __launch_bounds__(256) void ln_kernel(const T* __restrict__ x,
                                                 const float* __restrict__ g,
                                                 const float* __restrict__ bta,
                                                 unsigned short* __restrict__ dst_bf,
                                                 float* __restrict__ mu_out,
                                                 float* __restrict__ rs_out) {
    int row = blockIdx.x, tid = threadIdx.x;
    int lane = tid & 63, wave = tid >> 6;
    const T* xr = x + (size_t)row * C_;
    __shared__ float s1[4], s2[4];
    float s = 0.f, sq = 0.f;
    for (int c = tid; c < C_; c += 256) { float v = ldval(xr, c); s += v; sq += v * v; }
    for (int off = 32; off; off >>= 1) { s += __shfl_xor(s, off); sq += __shfl_xor(sq, off); }
    if (lane == 0) { s1[wave] = s; s2[wave] = sq; }
    __syncthreads();
    float ts = s1[0] + s1[1] + s1[2] + s1[3];
    float tq = s2[0] + s2[1] + s2[2] + s2[3];
    float mean = ts / (float)C_;
    float var = tq / (float)C_ - mean * mean;
    float rs = rsqrtf(var + 1e-6f);
    if (mu_out && tid == 0) { mu_out[row] = mean; rs_out[row] = rs; }
    if (dst_bf) {
        for (int c = tid; c < C_; c += 256) {
            float v = (ldval(xr, c) - mean) * rs * g[c] + bta[c];
            dst_bf[(size_t)row * C_ + c] = f2bf(v);
        }
    }
}

// ---------------- GEMM (m97 structure): C[m,n] = sum_k A[m,k]*B[n,k], bf16 in ----------------
template<int MODE, int MI>
__global__ __launch_bounds__(256) void gemm_kernel(const unsigned short* __restrict__ A,
                                                   const unsigned short* __restrict__ Bm,
                                                   const float* __restrict__ bias,
                                                   const float* __restrict__ residf,
                                                   const unsigned short* __restrict__ residb,
                                                   unsigned short* __restrict__ outb,
                                                   unsigned short* __restrict__ qd,
                                                   unsigned short* __restrict__ kd,
                                                   unsigned short* __restrict__ vd,
                                                   int M, int N, int K) {
    constexpr int TILE = MI * 32;
    __shared__ unsigned short As[TILE * 32];
    __shared__ unsigned short Bs[TILE * 32];
    int bid = blockIdx.x;
    int NT = N / TILE;
    int mt = bid / NT, nt = bid % NT;
    int m0 = mt * TILE, n0 = nt * TILE;
    int tid = threadIdx.x, lane = tid & 63, wave = tid >> 6;
    int ml = lane & 15, quad = lane >> 4;
    int srow = wave * 16 + (lane >> 2);
    int skc = (lane & 3) * 8;
    const unsigned short* ag[MI / 2 == 0 ? 1 : MI / 2];
    const unsigned short* bg[MI / 2 == 0 ? 1 : MI / 2];
#pragma unroll
    for (int jj = 0; jj < MI / 2; ++jj) {
        ag[jj] = A + (size_t)min(m0 + jj * 64 + srow, M - 1) * K + skc;
        bg[jj] = Bm + (size_t)(n0 + jj * 64 + srow) * K + skc;
    }
    int msub = (wave & 1) * (MI * 16), nsub = (wave >> 1) * (MI * 16);
    f32x4 acc[MI][MI] = {};
    for (int k0 = 0; k0 < K; k0 += 32) {
        __syncthreads();
#pragma unroll
        for (int jj = 0; jj < MI / 2; ++jj) {
            gload_lds16(ag[jj] + k0, As + jj * 2048 + wave * 512);
            gload_lds16(bg[jj] + k0, Bs + jj * 2048 + wave * 512);
        }
        asm volatile("s_waitcnt vmcnt(0)" ::: "memory");
        __syncthreads();
        bf16x8 af[MI], bfm[MI];
#pragma unroll
        for (int i = 0; i < MI; ++i) af[i] = ld_frag(As + (msub + 16 * i + ml) * 32 + quad * 8);
#pragma unroll
        for (int j = 0; j < MI; ++j) bfm[j] = ld_frag(Bs + (nsub + 16 * j + ml) * 32 + quad * 8);
#pragma unroll
        for (int i = 0; i < MI; ++i)
#pragma unroll
            for (int j = 0; j < MI; ++j)
                acc[i][j] = __builtin_amdgcn_mfma_f32_16x16x32_bf16(af[i], bfm[j], acc[i][j], 0, 0, 0);
    }
#pragma unroll
    for (int i = 0; i < MI; ++i)
#pragma unroll
    for (int j = 0; j < MI; ++j)
#pragma unroll
    for (int r = 0; r < 4; ++r) {
        int row = m0 + msub + 16 * i + quad * 4 + r;
        if (row >= M) continue;
        int col = n0 + nsub + 16 * j + ml;
        float v = acc[i][j][r] + bias[col];
        if (MODE == 0) {
            int b = row / N_, t = row - b * N_;
            int f = col;
            if (f < 768) {
                qd[((size_t)(b * H_ + (f >> 6)) * N_ + t) * HD_ + (f & 63)] = f2bf(v * 0.125f);
            } else if (f < 1536) {
                f -= 768;
                kd[((size_t)(b * H_ + (f >> 6)) * N_ + t) * HD_ + (f & 63)] = f2bf(v);
            } else {
                f -= 1536;
                vd[((size_t)(b * H_ + (f >> 6)) * HD_ + (f & 63)) * NP_ + t] = f2bf(v);
            }
        } else if (MODE == 1) {
            outb[(size_t)row * N + col] = f2bf(v + residf[(size_t)row * N + col]);
        } else if (MODE == 2) {
            float gl = 0.5f * v * (1.f + erff(v * 0.70710678118654752f));
            outb[(size_t)row * N + col] = f2bf(gl);
        } else {
            outb[(size_t)row * N + col] = f2bf(v + bf2f(residb[(size_t)row * N + col]));
        }
    }
}

// ---------------- fused masked attention (per 16-row q tile, register-resident S) ----------------
// Swizzle: bid = ((bh>>3)*37 + qt)*8 + (bh&7).  With XCD = bid%8 round-robin, each XCD
// runs the 37 q-tiles of its bh's back-to-back -> K/V stay resident in that XCD's L2.
__global__ __launch_bounds__(256, 3) void attn_kernel(const unsigned short* __restrict__ qb,
                                                      const unsigned short* __restrict__ kb,
                                                      const unsigned short* __restrict__ vt,
                                                      const float* __restrict__ maskf,
                                                      unsigned short* __restrict__ ybf) {
    int bid = blockIdx.x;
    int xcd = bid & 7, g = bid >> 3;
    int bh = (g / NQT_) * 8 + xcd;
    int qt = g % NQT_;
    int h = bh % H_, b = bh / H_;
    int q0 = qt * QT_;
    int tid = threadIdx.x, lane = tid & 63, wave = tid >> 6;
    int ml = lane & 15, quad = lane >> 4, kq = quad * 8;
    __shared__ __align__(16) unsigned short P[QT_][616];   // 19.7 KB transpose buffer
    __shared__ float wred[4][QT_];

    const float* bmask = maskf + (size_t)b * N_;
    float mrowv[4];
#pragma unroll
    for (int r = 0; r < 4; ++r) {
        int t = q0 + quad * 4 + r;
        mrowv[r] = (t < N_) ? bmask[t] : 0.f;
    }
    // phase 1: S tiles in registers (C-layout: lane holds rows quad*4+r, col = nt*16+ml)
    const unsigned short* qbase = qb + (size_t)(b * H_ + h) * N_ * HD_;
    const unsigned short* kbase = kb + (size_t)(b * H_ + h) * N_ * HD_;
    int qrow = min(q0 + ml, N_ - 1);
    bf16x8 aq0 = ld_frag(qbase + (size_t)qrow * HD_ + kq);
    bf16x8 aq1 = ld_frag(qbase + (size_t)qrow * HD_ + kq + 32);
    float sreg[10][4];
#pragma unroll
    for (int t = 0; t < 10; ++t) {
        int nt = wave + 4 * t;
        if (nt < NP_ / 16) {
            int colb = nt * 16;
            int krow = min(colb + ml, N_ - 1);
            bf16x8 bk0 = ld_frag(kbase + (size_t)krow * HD_ + kq);
            bf16x8 bk1 = ld_frag(kbase + (size_t)krow * HD_ + kq + 32);
            f32x4 a = {0.f, 0.f, 0.f, 0.f};
            a = __builtin_amdgcn_mfma_f32_16x16x32_bf16(aq0, bk0, a, 0, 0, 0);
            a = __builtin_amdgcn_mfma_f32_16x16x32_bf16(aq1, bk1, a, 0, 0, 0);
            bool keep = (colb + ml < N_) && (bmask[colb + ml] > 0.f);
#pragma unroll
            for (int r = 0; r < 4; ++r) sreg[t][r] = keep ? a[r] : -1e9f;
        } else {
#pragma unroll
            for (int r = 0; r < 4; ++r) sreg[t][r] = -1e9f;
        }
    }
    // phase 2: softmax; row spread over ml-lanes (shfl) and waves (wred)
    float lm[4];
#pragma unroll
    for (int r = 0; r < 4; ++r) {
        lm[r] = -3.4e38f;
#pragma unroll
        for (int t = 0; t < 10; ++t) lm[r] = fmaxf(lm[r], sreg[t][r]);
#pragma unroll
        for (int off = 1; off < 16; off <<= 1) lm[r] = fmaxf(lm[r], __shfl_xor(lm[r], off));
    }
    if (ml == 0) {
#pragma unroll
        for (int r = 0; r < 4; ++r) wred[wave][quad * 4 + r] = lm[r];
    }
    __syncthreads();
    float rmax[4], ls[4];
#pragma unroll
    for (int r = 0; r < 4; ++r) {
        int row = quad * 4 + r;
        rmax[r] = fmaxf(fmaxf(wred[0][row], wred[1][row]), fmaxf(wred[2][row], wred[3][row]));
        ls[r] = 0.f;
#pragma unroll
        for (int t = 0; t < 10; ++t) {
            float e = __expf(sreg[t][r] - rmax[r]);
            sreg[t][r] = e;
            ls[r] += e;
        }
#pragma unroll
        for (int off = 1; off < 16; off <<= 1) ls[r] += __shfl_xor(ls[r], off);
    }
    __syncthreads();             // all rmax reads done before wred reuse
    if (ml == 0) {
#pragma unroll
        for (int r = 0; r < 4; ++r) wred[wave][quad * 4 + r] = ls[r];
    }
    __syncthreads();
#pragma unroll
    for (int r = 0; r < 4; ++r) {
        int row = quad * 4 + r;
        float sum = wred[0][row] + wred[1][row] + wred[2][row] + wred[3][row];
        float inv = mrowv[r] / sum;   // masked q-rows -> all-zero P row
#pragma unroll
        for (int t = 0; t < 10; ++t) {
            int nt = wave + 4 * t;
            if (nt < NP_ / 16) P[row][nt * 16 + ml] = f2bf(sreg[t][r] * inv);
        }
    }
    __syncthreads();
    // phase 3: O = P @ V (V transposed [b,h,d,t]; loads are XCD-L2 hits)
    const unsigned short* vrow = vt + ((size_t)(b * H_ + h) * HD_ + wave * 16 + ml) * NP_ + kq;
    f32x4 acc = {0.f, 0.f, 0.f, 0.f};
#pragma unroll
    for (int t = 0; t < 19; ++t) {
        bf16x8 pa = ld_frag(&P[ml][kq + t * 32]);
        bf16x8 vb = ld_frag(vrow + t * 32);
        acc = __builtin_amdgcn_mfma_f32_16x16x32_bf16(pa, vb, acc, 0, 0, 0);
    }
#pragma unroll
    for (int r = 0; r < 4; ++r) {
        int t = q0 + quad * 4 + r;
        if (t < N_)
            ybf[((size_t)(b * N_ + t)) * C_ + h * HD_ + wave * 16 + ml] = f2bf(acc[r]);
    }
}

// ---------------- masked pooled raw sums of bbn-normalized x2 ----------------
__global__ __launch_bounds__(256) void pool_kernel(const unsigned short* __restrict__ x2,
                                                   const float* __restrict__ mu,
                                                   const float* __restrict__ rs,
                                                   const float* __restrict__ maskf,
                                                   float* __restrict__ praw) {
    int c = blockIdx.x * 256 + threadIdx.x;
    int tchunk = blockIdx.y;
    int b = blockIdx.z;
    int t0 = tchunk * 73, t1 = min(t0 + 73, N_);
    float s = 0.f;
    for (int t = t0; t < t1; ++t) {
        int row = b * N_ + t;
        float m = maskf[row];
        if (m > 0.f) s += (bf2f(x2[(size_t)row * C_ + c]) - mu[row]) * rs[row];
    }
    atomicAdd(&praw[b * C_ + c], s);
}

// ---------------- finish: bbn affine + /cnt, then final LN -> out ----------------
__global__ __launch_bounds__(256) void final_kernel(const float* __restrict__ praw,
                                                    const float* __restrict__ cnt,
                                                    const float* __restrict__ bg,
                                                    const float* __restrict__ bb,
                                                    const float* __restrict__ og,
                                                    const float* __restrict__ ob,
                                                    float* __restrict__ out) {
    int b = blockIdx.x, tid = threadIdx.x;
    int lane = tid & 63, wave = tid >> 6;
    __shared__ float u[C_];
    __shared__ float r1[4], r2[4];
    float inv = 1.f / cnt[b];
    float s = 0.f, sq = 0.f;
    for (int c = tid; c < C_; c += 256) {
        float v = bg[c] * praw[b * C_ + c] * inv + bb[c];
        u[c] = v; s += v; sq += v * v;
    }
    for (int off = 32; off; off >>= 1) { s += __shfl_xor(s, off); sq += __shfl_xor(sq, off); }
    if (lane == 0) { r1[wave] = s; r2[wave] = sq; }
    __syncthreads();
    float ts = r1[0] + r1[1] + r1[2] + r1[3];
    float tq = r2[0] + r2[1] + r2[2] + r2[3];
    float mean = ts / (float)C_;
    float var = tq / (float)C_ - mean * mean;
    float rstd = rsqrtf(var + 1e-6f);
    for (int c = tid; c < C_; c += 256)
        out[b * C_ + c] = (u[c] - mean) * rstd * og[c] + ob[c];
}

extern "C" void kernel_launch(void* const* d_in, const int* in_sizes, int n_in,
                              void* d_out, int out_size, void* d_ws, size_t ws_size,
                              hipStream_t stream) {
    const float* last_x  = (const float*)d_in[0];
    const float* scores  = (const float*)d_in[1];
    const float* n1g     = (const float*)d_in[2];
    const float* n1b     = (const float*)d_in[3];
    const float* qkv_w   = (const float*)d_in[4];
    const float* qkv_b   = (const float*)d_in[5];
    const float* proj_w  = (const float*)d_in[6];
    const float* proj_b  = (const float*)d_in[7];
    const float* n2g     = (const float*)d_in[8];
    const float* n2b     = (const float*)d_in[9];
    const float* fc1_w   = (const float*)d_in[10];
    const float* fc1_b   = (const float*)d_in[11];
    const float* fc2_w   = (const float*)d_in[12];
    const float* fc2_b   = (const float*)d_in[13];
    const float* bbn_g   = (const float*)d_in[14];
    const float* bbn_b   = (const float*)d_in[15];
    const float* out_g   = (const float*)d_in[16];
    const float* out_b   = (const float*)d_in[17];
    float* out = (float*)d_out;

    char* w = (char*)d_ws;
    size_t off = 0;
    auto alloc = [&](size_t bytes) -> char* {
        off = (off + 255) & ~(size_t)255;
        char* p = w + off;
        off += bytes;
        return p;
    };
    unsigned short* wq = (unsigned short*)alloc((size_t)2304 * 768 * 2);
    unsigned short* wp = (unsigned short*)alloc((size_t)768 * 768 * 2);
    unsigned short* w1 = (unsigned short*)alloc((size_t)3072 * 768 * 2);
    unsigned short* w2 = (unsigned short*)alloc((size_t)768 * 3072 * 2);
    float* maskf = (float*)alloc((size_t)M_ * 4);
    float* cnt   = (float*)alloc(32 * 4);
    float* mu    = (float*)alloc((size_t)M_ * 4);
    float* rs    = (float*)alloc((size_t)M_ * 4);
    float* praw  = (float*)alloc((size_t)B_ * C_ * 4);
    unsigned short* h_bf = (unsigned short*)alloc((size_t)M_ * C_ * 2);            // h -> y -> act_chunk
    unsigned short* q_bf = (unsigned short*)alloc((size_t)B_ * H_ * N_ * HD_ * 2); // q -> m (LN2 out)
    unsigned short* k_bf = (unsigned short*)alloc((size_t)B_ * H_ * N_ * HD_ * 2); // k -> x2 (bf16)
    unsigned short* vt   = (unsigned short*)alloc((size_t)B_ * H_ * HD_ * NP_ * 2); // vt -> x1 (bf16)
    unsigned short* y_bf = h_bf;
    unsigned short* m_bf = q_bf;
    unsigned short* x1   = vt;
    unsigned short* x2   = k_bf;
    unsigned short* act  = h_bf;

    // 1. cast weights to bf16 (single merged launch)
    cast4_kernel<<<6912, 256, 0, stream>>>(qkv_w, proj_w, fc1_w, fc2_w, wq, wp, w1, w2);
    // 2. prune mask
    prune_kernel<<<B_, 256, 0, stream>>>(scores, maskf, cnt);
    // 3. LN1 -> h (bf16)
    ln_kernel<float><<<M_, 256, 0, stream>>>(last_x, n1g, n1b, h_bf, nullptr, nullptr);
    // 4. QKV gemm (128-tile), split store
    gemm_kernel<0, 4><<<((M_ + 127) / 128) * (2304 / 128), 256, 0, stream>>>(
        h_bf, wq, qkv_b, nullptr, nullptr, nullptr, q_bf, k_bf, vt, M_, 2304, C_);
    // 5. masked attention -> y
    attn_kernel<<<B_ * H_ * NQT_, 256, 0, stream>>>(q_bf, k_bf, vt, maskf, y_bf);
    // 6. proj gemm + residual(f32 last_x) -> x1 (bf16)
    gemm_kernel<1, 4><<<((M_ + 127) / 128) * (768 / 128), 256, 0, stream>>>(
        y_bf, wp, proj_b, last_x, nullptr, x1, nullptr, nullptr, nullptr, M_, C_, C_);
    // 7. LN2 -> m (bf16)
    ln_kernel<unsigned short><<<M_, 256, 0, stream>>>(x1, n2g, n2b, m_bf, nullptr, nullptr);
    // 8/9. MLP in 4 row-chunks; fc2 uses 64-tile for block count
    for (int c = 0; c < 4; ++c) {
        int r0 = c * MCH_;
        gemm_kernel<2, 4><<<((MCH_ + 127) / 128) * (3072 / 128), 256, 0, stream>>>(
            m_bf + (size_t)r0 * C_, w1, fc1_b, nullptr, nullptr, act,
            nullptr, nullptr, nullptr, MCH_, 3072, C_);
        gemm_kernel<3, 2><<<((MCH_ + 63) / 64) * (768 / 64), 256, 0, stream>>>(
            act, w2, fc2_b, nullptr, x1 + (size_t)r0 * C_, x2 + (size_t)r0 * C_,
            nullptr, nullptr, nullptr, MCH_, 768, 3072);
    }
    // 10. bbn LN stats only
    ln_kernel<unsigned short><<<M_, 256, 0, stream>>>(x2, bbn_g, bbn_b, nullptr, mu, rs);
    // 11. masked pooled raw sums
    hipMemsetAsync(praw, 0, (size_t)B_ * C_ * 4, stream);
    dim3 pg(3, 8, B_);
    pool_kernel<<<pg, 256, 0, stream>>>(x2, mu, rs, maskf, praw);
    // 12. bbn affine + /cnt + final LN -> out
    final_kernel<<<B_, 256, 0, stream>>>(praw, cnt, bbn_g, bbn_b, out_g, out_b, out);
    (void)in_sizes; (void)n_in; (void)out_size; (void)ws_size;
}

// Round 5
// 1215.421 us; speedup vs baseline: 2.3107x; 1.1377x over previous
//
#include <hip/hip_runtime.h>

#define B_   32
#define L_   11
#define N_   577
#define C_   768
#define H_   12
#define HD_  64
#define M_   (B_ * N_)      // 18464
#define NP_  608            // padded key count (19*32)
#define QT_  16             // q rows per attention block
#define NQT_ 37             // ceil(577/16)
#define MCH_ 4616           // M_/4 rows per MLP chunk (fallback path)

typedef unsigned int uint32;

typedef short bf16x8 __attribute__((ext_vector_type(8)));
typedef float f32x4  __attribute__((ext_vector_type(4)));

__device__ __forceinline__ unsigned short f2bf(float f) {
    union { float f; uint32 u; } c; c.f = f;
    uint32 u = c.u;
    uint32 r = (u + 0x7FFFu + ((u >> 16) & 1u)) >> 16;
    return (unsigned short)r;
}
__device__ __forceinline__ float bf2f(unsigned short u) {
    union { uint32 u; float f; } c; c.u = ((uint32)u) << 16;
    return c.f;
}
__device__ __forceinline__ float ldval(const float* p, size_t i) { return p[i]; }
__device__ __forceinline__ float ldval(const unsigned short* p, size_t i) { return bf2f(p[i]); }

__device__ __forceinline__ bf16x8 ld_frag(const unsigned short* p) {
    union { uint4 u; bf16x8 v; } c;
    c.u = *reinterpret_cast<const uint4*>(p);
    return c.v;
}

// async global->LDS, 16B per lane; LDS dest is wave-uniform base + lane*16
__device__ __forceinline__ void gload_lds16(const unsigned short* g, unsigned short* l) {
    __builtin_amdgcn_global_load_lds(
        (const __attribute__((address_space(1))) unsigned int*)g,
        (__attribute__((address_space(3))) unsigned int*)l, 16, 0, 0);
}

// ---------------- merged cast fp32 -> bf16 (all 4 weight mats, float4-vectorized) ----------------
__global__ __launch_bounds__(256) void cast4_kernel(const float* __restrict__ qkvw,
                                                    const float* __restrict__ projw,
                                                    const float* __restrict__ fc1w,
                                                    const float* __restrict__ fc2w,
                                                    unsigned short* __restrict__ dq,
                                                    unsigned short* __restrict__ dp,
                                                    unsigned short* __restrict__ d1,
                                                    unsigned short* __restrict__ d2) {
    int i = blockIdx.x * 256 + threadIdx.x;     // vec4 index; total 1,769,472
    const int N0 = 442368, N1 = 147456, N2 = 589824;
    const float* s; unsigned short* d; int j;
    if (i < N0)                { s = qkvw; d = dq; j = i; }
    else if (i < N0 + N1)      { s = projw; d = dp; j = i - N0; }
    else if (i < N0 + N1 + N2) { s = fc1w;  d = d1; j = i - N0 - N1; }
    else                       { s = fc2w;  d = d2; j = i - N0 - N1 - N2; }
    float4 v = reinterpret_cast<const float4*>(s)[j];
    union { unsigned short us[4]; uint2 u; } o;
    o.us[0] = f2bf(v.x); o.us[1] = f2bf(v.y); o.us[2] = f2bf(v.z); o.us[3] = f2bf(v.w);
    reinterpret_cast<uint2*>(d)[j] = o.u;
}

// ---------------- prune: token mask ----------------
__global__ __launch_bounds__(256) void prune_kernel(const float* __restrict__ scores,
                                                    float* __restrict__ maskf,
                                                    float* __restrict__ cnt) {
    int b = blockIdx.x, tid = threadIdx.x;
    int lane = tid & 63, wave = tid >> 6;
    __shared__ float ps[576];
    __shared__ float red[4];
    for (int j = tid; j < 576; j += 256) ps[j] = 0.f;
    __syncthreads();
    for (int l = 0; l < L_; ++l) {
        const float* row = scores + ((size_t)b * L_ + l) * N_ + 1;
        float mx = -3.4e38f;
        for (int j = tid; j < 576; j += 256) mx = fmaxf(mx, row[j]);
        for (int off = 32; off; off >>= 1) mx = fmaxf(mx, __shfl_xor(mx, off));
        if (lane == 0) red[wave] = mx;
        __syncthreads();
        mx = fmaxf(fmaxf(red[0], red[1]), fmaxf(red[2], red[3]));
        __syncthreads();
        float s = 0.f;
        for (int j = tid; j < 576; j += 256) s += expf(row[j] - mx);
        for (int off = 32; off; off >>= 1) s += __shfl_xor(s, off);
        if (lane == 0) red[wave] = s;
        __syncthreads();
        s = red[0] + red[1] + red[2] + red[3];
        float inv = 1.f / s;
        for (int j = tid; j < 576; j += 256) ps[j] += expf(row[j] - mx) * inv;
        __syncthreads();
    }
    for (int j = tid; j < 576; j += 256) ps[j] = ps[j] / 11.0f;
    __syncthreads();
    int kept = 0;
    for (int i = tid; i < 576; i += 256) {
        float vi = ps[i];
        float s = 0.f;
        for (int j = 0; j < 576; ++j) {
            float vj = ps[j];
            if (vj < vi || (vj == vi && j <= i)) s += vj;
        }
        int k = (s > 0.5f) ? 1 : 0;
        maskf[b * N_ + 1 + i] = (float)k;
        kept += k;
    }
    __syncthreads();
    for (int off = 32; off; off >>= 1) kept += __shfl_xor(kept, off);
    if (lane == 0) red[wave] = (float)kept;
    __syncthreads();
    if (tid == 0) {
        cnt[b] = red[0] + red[1] + red[2] + red[3] + 1.f;  // +CLS
        maskf[b * N_] = 1.f;
    }
}

// ---------------- layer norm (row-wise): optional bf16 out, optional stats ----------------
template<typename T>
__global__ __launch_bounds__(256) void ln_kernel(const T* __restrict__ x,
                                                 const float* __restrict__ g,
                                                 const float* __restrict__ bta,
                                                 unsigned short* __restrict__ dst_bf,
                                                 float* __restrict__ mu_out,
                                                 float* __restrict__ rs_out) {
    int row = blockIdx.x, tid = threadIdx.x;
    int lane = tid & 63, wave = tid >> 6;
    const T* xr = x + (size_t)row * C_;
    __shared__ float s1[4], s2[4];
    float s = 0.f, sq = 0.f;
    for (int c = tid; c < C_; c += 256) { float v = ldval(xr, c); s += v; sq += v * v; }
    for (int off = 32; off; off >>= 1) { s += __shfl_xor(s, off); sq += __shfl_xor(sq, off); }
    if (lane == 0) { s1[wave] = s; s2[wave] = sq; }
    __syncthreads();
    float ts = s1[0] + s1[1] + s1[2] + s1[3];
    float tq = s2[0] + s2[1] + s2[2] + s2[3];
    float mean = ts / (float)C_;
    float var = tq / (float)C_ - mean * mean;
    float rs = rsqrtf(var + 1e-6f);
    if (mu_out && tid == 0) { mu_out[row] = mean; rs_out[row] = rs; }
    if (dst_bf) {
        for (int c = tid; c < C_; c += 256) {
            float v = (ldval(xr, c) - mean) * rs * g[c] + bta[c];
            dst_bf[(size_t)row * C_ + c] = f2bf(v);
        }
    }
}

// ---------------- GEMM (m97 structure): C[m,n] = sum_k A[m,k]*B[n,k], bf16 in ----------------
template<int MODE, int MI>
__global__ __launch_bounds__(256) void gemm_kernel(const unsigned short* __restrict__ A,
                                                   const unsigned short* __restrict__ Bm,
                                                   const float* __restrict__ bias,
                                                   const float* __restrict__ residf,
                                                   const unsigned short* __restrict__ residb,
                                                   unsigned short* __restrict__ outb,
                                                   unsigned short* __restrict__ qd,
                                                   unsigned short* __restrict__ kd,
                                                   unsigned short* __restrict__ vd,
                                                   int M, int N, int K) {
    constexpr int TILE = MI * 32;
    __shared__ unsigned short As[TILE * 32];
    __shared__ unsigned short Bs[TILE * 32];
    int bid = blockIdx.x;
    int NT = N / TILE;
    int mt = bid / NT, nt = bid % NT;
    int m0 = mt * TILE, n0 = nt * TILE;
    int tid = threadIdx.x, lane = tid & 63, wave = tid >> 6;
    int ml = lane & 15, quad = lane >> 4;
    int srow = wave * 16 + (lane >> 2);
    int skc = (lane & 3) * 8;
    const unsigned short* ag[MI / 2 == 0 ? 1 : MI / 2];
    const unsigned short* bg[MI / 2 == 0 ? 1 : MI / 2];
#pragma unroll
    for (int jj = 0; jj < MI / 2; ++jj) {
        ag[jj] = A + (size_t)min(m0 + jj * 64 + srow, M - 1) * K + skc;
        bg[jj] = Bm + (size_t)(n0 + jj * 64 + srow) * K + skc;
    }
    int msub = (wave & 1) * (MI * 16), nsub = (wave >> 1) * (MI * 16);
    f32x4 acc[MI][MI] = {};
    for (int k0 = 0; k0 < K; k0 += 32) {
        __syncthreads();
#pragma unroll
        for (int jj = 0; jj < MI / 2; ++jj) {
            gload_lds16(ag[jj] + k0, As + jj * 2048 + wave * 512);
            gload_lds16(bg[jj] + k0, Bs + jj * 2048 + wave * 512);
        }
        asm volatile("s_waitcnt vmcnt(0)" ::: "memory");
        __syncthreads();
        bf16x8 af[MI], bfm[MI];
#pragma unroll
        for (int i = 0; i < MI; ++i) af[i] = ld_frag(As + (msub + 16 * i + ml) * 32 + quad * 8);
#pragma unroll
        for (int j = 0; j < MI; ++j) bfm[j] = ld_frag(Bs + (nsub + 16 * j + ml) * 32 + quad * 8);
#pragma unroll
        for (int i = 0; i < MI; ++i)
#pragma unroll
            for (int j = 0; j < MI; ++j)
                acc[i][j] = __builtin_amdgcn_mfma_f32_16x16x32_bf16(af[i], bfm[j], acc[i][j], 0, 0, 0);
    }
#pragma unroll
    for (int i = 0; i < MI; ++i)
#pragma unroll
    for (int j = 0; j < MI; ++j)
#pragma unroll
    for (int r = 0; r < 4; ++r) {
        int row = m0 + msub + 16 * i + quad * 4 + r;
        if (row >= M) continue;
        int col = n0 + nsub + 16 * j + ml;
        float v = acc[i][j][r] + bias[col];
        if (MODE == 0) {
            int b = row / N_, t = row - b * N_;
            int f = col;
            if (f < 768) {
                qd[((size_t)(b * H_ + (f >> 6)) * N_ + t) * HD_ + (f & 63)] = f2bf(v * 0.125f);
            } else if (f < 1536) {
                f -= 768;
                kd[((size_t)(b * H_ + (f >> 6)) * N_ + t) * HD_ + (f & 63)] = f2bf(v);
            } else {
                f -= 1536;
                vd[((size_t)(b * H_ + (f >> 6)) * HD_ + (f & 63)) * NP_ + t] = f2bf(v);
            }
        } else if (MODE == 1) {
            outb[(size_t)row * N + col] = f2bf(v + residf[(size_t)row * N + col]);
        } else if (MODE == 2) {
            float gl = 0.5f * v * (1.f + erff(v * 0.70710678118654752f));
            outb[(size_t)row * N + col] = f2bf(gl);
        } else {
            outb[(size_t)row * N + col] = f2bf(v + bf2f(residb[(size_t)row * N + col]));
        }
    }
}

// ---------------- fused masked attention: 1-barrier version ----------------
// No max-subtraction (|S|<~5 by construction: LN'd inputs x 0.02-scaled weights -> exp safe).
// P stored as raw exp (unscaled bf16); 1/sum and the q-row mask applied to the O accumulator.
// Swizzle: bid = ((bh>>3)*37 + qt)*8 + (bh&7) keeps each (b,h)'s K/V in one XCD's L2.
__global__ __launch_bounds__(256, 4) void attn_kernel(const unsigned short* __restrict__ qb,
                                                      const unsigned short* __restrict__ kb,
                                                      const unsigned short* __restrict__ vt,
                                                      const float* __restrict__ maskf,
                                                      unsigned short* __restrict__ ybf) {
    int bid = blockIdx.x;
    int xcd = bid & 7, g = bid >> 3;
    int bh = (g / NQT_) * 8 + xcd;
    int qt = g % NQT_;
    int h = bh % H_, b = bh / H_;
    int q0 = qt * QT_;
    int tid = threadIdx.x, lane = tid & 63, wave = tid >> 6;
    int ml = lane & 15, quad = lane >> 4, kq = quad * 8;
    __shared__ __align__(16) unsigned short P[QT_][616];
    __shared__ float wred[4][QT_];

    const float* bmask = maskf + (size_t)b * N_;
    float mrowv[4];
#pragma unroll
    for (int r = 0; r < 4; ++r) {
        int t = q0 + quad * 4 + r;
        mrowv[r] = (t < N_) ? bmask[t] : 0.f;
    }
    // phase 1: S tiles in registers, exp inline, masked keys -> 0
    const unsigned short* qbase = qb + (size_t)(b * H_ + h) * N_ * HD_;
    const unsigned short* kbase = kb + (size_t)(b * H_ + h) * N_ * HD_;
    int qrow = min(q0 + ml, N_ - 1);
    bf16x8 aq0 = ld_frag(qbase + (size_t)qrow * HD_ + kq);
    bf16x8 aq1 = ld_frag(qbase + (size_t)qrow * HD_ + kq + 32);
    float sreg[10][4];
    float ls[4] = {0.f, 0.f, 0.f, 0.f};
#pragma unroll
    for (int t = 0; t < 10; ++t) {
        int nt = wave + 4 * t;
        if (nt < NP_ / 16) {
            int col = nt * 16 + ml;
            int krow = min(col, N_ - 1);
            bf16x8 bk0 = ld_frag(kbase + (size_t)krow * HD_ + kq);
            bf16x8 bk1 = ld_frag(kbase + (size_t)krow * HD_ + kq + 32);
            f32x4 a = {0.f, 0.f, 0.f, 0.f};
            a = __builtin_amdgcn_mfma_f32_16x16x32_bf16(aq0, bk0, a, 0, 0, 0);
            a = __builtin_amdgcn_mfma_f32_16x16x32_bf16(aq1, bk1, a, 0, 0, 0);
            bool keep = (col < N_) && (bmask[col] > 0.f);
#pragma unroll
            for (int r = 0; r < 4; ++r) {
                float e = keep ? __expf(a[r]) : 0.f;
                sreg[t][r] = e;
                ls[r] += e;
            }
        } else {
#pragma unroll
            for (int r = 0; r < 4; ++r) sreg[t][r] = 0.f;
        }
    }
    // in-wave sum over ml lanes, then single cross-wave round
#pragma unroll
    for (int r = 0; r < 4; ++r) {
#pragma unroll
        for (int off = 1; off < 16; off <<= 1) ls[r] += __shfl_xor(ls[r], off);
    }
    if (ml == 0) {
#pragma unroll
        for (int r = 0; r < 4; ++r) wred[wave][quad * 4 + r] = ls[r];
    }
    // write raw-exp P (unscaled)
#pragma unroll
    for (int t = 0; t < 10; ++t) {
        int nt = wave + 4 * t;
        if (nt < NP_ / 16) {
#pragma unroll
            for (int r = 0; r < 4; ++r) P[quad * 4 + r][nt * 16 + ml] = f2bf(sreg[t][r]);
        }
    }
    __syncthreads();   // the ONLY barrier
    float inv[4];
#pragma unroll
    for (int r = 0; r < 4; ++r) {
        int row = quad * 4 + r;
        float sum = wred[0][row] + wred[1][row] + wred[2][row] + wred[3][row];
        inv[r] = mrowv[r] / sum;    // masked q-rows -> 0 (sum>0: CLS key always kept)
    }
    // phase 3: O = P @ V, scale by inv in epilogue
    const unsigned short* vrow = vt + ((size_t)(b * H_ + h) * HD_ + wave * 16 + ml) * NP_ + kq;
    f32x4 acc = {0.f, 0.f, 0.f, 0.f};
#pragma unroll
    for (int t = 0; t < 19; ++t) {
        bf16x8 pa = ld_frag(&P[ml][kq + t * 32]);
        bf16x8 vb = ld_frag(vrow + t * 32);
        acc = __builtin_amdgcn_mfma_f32_16x16x32_bf16(pa, vb, acc, 0, 0, 0);
    }
#pragma unroll
    for (int r = 0; r < 4; ++r) {
        int t = q0 + quad * 4 + r;
        if (t < N_)
            ybf[((size_t)(b * N_ + t)) * C_ + h * HD_ + wave * 16 + ml] = f2bf(acc[r] * inv[r]);
    }
}

// ---------------- masked pooled raw sums of bbn-normalized x2 ----------------
__global__ __launch_bounds__(256) void pool_kernel(const unsigned short* __restrict__ x2,
                                                   const float* __restrict__ mu,
                                                   const float* __restrict__ rs,
                                                   const float* __restrict__ maskf,
                                                   float* __restrict__ praw) {
    int c = blockIdx.x * 256 + threadIdx.x;
    int tchunk = blockIdx.y;
    int b = blockIdx.z;
    int t0 = tchunk * 73, t1 = min(t0 + 73, N_);
    float s = 0.f;
    for (int t = t0; t < t1; ++t) {
        int row = b * N_ + t;
        float m = maskf[row];
        if (m > 0.f) s += (bf2f(x2[(size_t)row * C_ + c]) - mu[row]) * rs[row];
    }
    atomicAdd(&praw[b * C_ + c], s);
}

// ---------------- finish: bbn affine + /cnt, then final LN -> out ----------------
__global__ __launch_bounds__(256) void final_kernel(const float* __restrict__ praw,
                                                    const float* __restrict__ cnt,
                                                    const float* __restrict__ bg,
                                                    const float* __restrict__ bb,
                                                    const float* __restrict__ og,
                                                    const float* __restrict__ ob,
                                                    float* __restrict__ out) {
    int b = blockIdx.x, tid = threadIdx.x;
    int lane = tid & 63, wave = tid >> 6;
    __shared__ float u[C_];
    __shared__ float r1[4], r2[4];
    float inv = 1.f / cnt[b];
    float s = 0.f, sq = 0.f;
    for (int c = tid; c < C_; c += 256) {
        float v = bg[c] * praw[b * C_ + c] * inv + bb[c];
        u[c] = v; s += v; sq += v * v;
    }
    for (int off = 32; off; off >>= 1) { s += __shfl_xor(s, off); sq += __shfl_xor(sq, off); }
    if (lane == 0) { r1[wave] = s; r2[wave] = sq; }
    __syncthreads();
    float ts = r1[0] + r1[1] + r1[2] + r1[3];
    float tq = r2[0] + r2[1] + r2[2] + r2[3];
    float mean = ts / (float)C_;
    float var = tq / (float)C_ - mean * mean;
    float rstd = rsqrtf(var + 1e-6f);
    for (int c = tid; c < C_; c += 256)
        out[b * C_ + c] = (u[c] - mean) * rstd * og[c] + ob[c];
}

extern "C" void kernel_launch(void* const* d_in, const int* in_sizes, int n_in,
                              void* d_out, int out_size, void* d_ws, size_t ws_size,
                              hipStream_t stream) {
    const float* last_x  = (const float*)d_in[0];
    const float* scores  = (const float*)d_in[1];
    const float* n1g     = (const float*)d_in[2];
    const float* n1b     = (const float*)d_in[3];
    const float* qkv_w   = (const float*)d_in[4];
    const float* qkv_b   = (const float*)d_in[5];
    const float* proj_w  = (const float*)d_in[6];
    const float* proj_b  = (const float*)d_in[7];
    const float* n2g     = (const float*)d_in[8];
    const float* n2b     = (const float*)d_in[9];
    const float* fc1_w   = (const float*)d_in[10];
    const float* fc1_b   = (const float*)d_in[11];
    const float* fc2_w   = (const float*)d_in[12];
    const float* fc2_b   = (const float*)d_in[13];
    const float* bbn_g   = (const float*)d_in[14];
    const float* bbn_b   = (const float*)d_in[15];
    const float* out_g   = (const float*)d_in[16];
    const float* out_b   = (const float*)d_in[17];
    float* out = (float*)d_out;

    char* w = (char*)d_ws;
    size_t off = 0;
    auto alloc = [&](size_t bytes) -> char* {
        off = (off + 255) & ~(size_t)255;
        char* p = w + off;
        off += bytes;
        return p;
    };
    unsigned short* wq = (unsigned short*)alloc((size_t)2304 * 768 * 2);
    unsigned short* wp = (unsigned short*)alloc((size_t)768 * 768 * 2);
    unsigned short* w1 = (unsigned short*)alloc((size_t)3072 * 768 * 2);
    unsigned short* w2 = (unsigned short*)alloc((size_t)768 * 3072 * 2);
    float* maskf = (float*)alloc((size_t)M_ * 4);
    float* cnt   = (float*)alloc(32 * 4);
    float* mu    = (float*)alloc((size_t)M_ * 4);
    float* rs    = (float*)alloc((size_t)M_ * 4);
    float* praw  = (float*)alloc((size_t)B_ * C_ * 4);
    unsigned short* h_bf = (unsigned short*)alloc((size_t)M_ * C_ * 2);            // h -> y -> act(fallback)
    unsigned short* q_bf = (unsigned short*)alloc((size_t)B_ * H_ * N_ * HD_ * 2); // q -> m (LN2 out)
    unsigned short* k_bf = (unsigned short*)alloc((size_t)B_ * H_ * N_ * HD_ * 2); // k -> x2 (bf16)
    unsigned short* vt   = (unsigned short*)alloc((size_t)B_ * H_ * HD_ * NP_ * 2); // vt -> x1 (bf16)
    unsigned short* y_bf = h_bf;
    unsigned short* m_bf = q_bf;
    unsigned short* x1   = vt;
    unsigned short* x2   = k_bf;

    // probe workspace: dedicated full-size act buffer if it fits (ws_size is fixed per session,
    // so the branch is deterministic across calls — no graph-capture hazard)
    size_t act_need = (size_t)M_ * 3072 * 2;
    bool big = (((off + 255) & ~(size_t)255) + act_need) <= ws_size;
    unsigned short* act = big ? (unsigned short*)alloc(act_need) : h_bf;

    // 1. cast weights to bf16 (single merged launch)
    cast4_kernel<<<6912, 256, 0, stream>>>(qkv_w, proj_w, fc1_w, fc2_w, wq, wp, w1, w2);
    // 2. prune mask
    prune_kernel<<<B_, 256, 0, stream>>>(scores, maskf, cnt);
    // 3. LN1 -> h (bf16)
    ln_kernel<float><<<M_, 256, 0, stream>>>(last_x, n1g, n1b, h_bf, nullptr, nullptr);
    // 4. QKV gemm (128-tile), split store
    gemm_kernel<0, 4><<<((M_ + 127) / 128) * (2304 / 128), 256, 0, stream>>>(
        h_bf, wq, qkv_b, nullptr, nullptr, nullptr, q_bf, k_bf, vt, M_, 2304, C_);
    // 5. masked attention -> y
    attn_kernel<<<B_ * H_ * NQT_, 256, 0, stream>>>(q_bf, k_bf, vt, maskf, y_bf);
    // 6. proj gemm + residual(f32 last_x) -> x1 (bf16)
    gemm_kernel<1, 4><<<((M_ + 127) / 128) * (768 / 128), 256, 0, stream>>>(
        y_bf, wp, proj_b, last_x, nullptr, x1, nullptr, nullptr, nullptr, M_, C_, C_);
    // 7. LN2 -> m (bf16)
    ln_kernel<unsigned short><<<M_, 256, 0, stream>>>(x1, n2g, n2b, m_bf, nullptr, nullptr);
    // 8/9. MLP: unchunked 128-tile if workspace allows, else 4 chunks at 128-tile
    if (big) {
        gemm_kernel<2, 4><<<((M_ + 127) / 128) * (3072 / 128), 256, 0, stream>>>(
            m_bf, w1, fc1_b, nullptr, nullptr, act, nullptr, nullptr, nullptr, M_, 3072, C_);
        gemm_kernel<3, 4><<<((M_ + 127) / 128) * (768 / 128), 256, 0, stream>>>(
            act, w2, fc2_b, nullptr, x1, x2, nullptr, nullptr, nullptr, M_, C_, 3072);
    } else {
        for (int c = 0; c < 4; ++c) {
            int r0 = c * MCH_;
            gemm_kernel<2, 4><<<((MCH_ + 127) / 128) * (3072 / 128), 256, 0, stream>>>(
                m_bf + (size_t)r0 * C_, w1, fc1_b, nullptr, nullptr, act,
                nullptr, nullptr, nullptr, MCH_, 3072, C_);
            gemm_kernel<3, 4><<<((MCH_ + 127) / 128) * (768 / 128), 256, 0, stream>>>(
                act, w2, fc2_b, nullptr, x1 + (size_t)r0 * C_, x2 + (size_t)r0 * C_,
                nullptr, nullptr, nullptr, MCH_, 768, 3072);
        }
    }
    // 10. bbn LN stats only
    ln_kernel<unsigned short><<<M_, 256, 0, stream>>>(x2, bbn_g, bbn_b, nullptr, mu, rs);
    // 11. masked pooled raw sums
    hipMemsetAsync(praw, 0, (size_t)B_ * C_ * 4, stream);
    dim3 pg(3, 8, B_);
    pool_kernel<<<pg, 256, 0, stream>>>(x2, mu, rs, maskf, praw);
    // 12. bbn affine + /cnt + final LN -> out
    final_kernel<<<B_, 256, 0, stream>>>(praw, cnt, bbn_g, bbn_b, out_g, out_b, out);
    (void)in_sizes; (void)n_in; (void)out_size;
}

// Round 6
// 1169.240 us; speedup vs baseline: 2.4020x; 1.0395x over previous
//
#include <hip/hip_runtime.h>

#define B_   32
#define L_   11
#define N_   577
#define C_   768
#define H_   12
#define HD_  64
#define M_   (B_ * N_)      // 18464
#define NP_  608            // padded key count (19*32)
#define QT_  32             // q rows per attention block
#define NQT_ 19             // ceil(577/32)
#define MCH_ 4616           // M_/4 rows per MLP chunk (fallback path)

typedef unsigned int uint32;

typedef short bf16x8 __attribute__((ext_vector_type(8)));
typedef float f32x4  __attribute__((ext_vector_type(4)));

__device__ __forceinline__ unsigned short f2bf(float f) {
    union { float f; uint32 u; } c; c.f = f;
    uint32 u = c.u;
    uint32 r = (u + 0x7FFFu + ((u >> 16) & 1u)) >> 16;
    return (unsigned short)r;
}
__device__ __forceinline__ float bf2f(unsigned short u) {
    union { uint32 u; float f; } c; c.u = ((uint32)u) << 16;
    return c.f;
}
__device__ __forceinline__ float ldval(const float* p, size_t i) { return p[i]; }
__device__ __forceinline__ float ldval(const unsigned short* p, size_t i) { return bf2f(p[i]); }

__device__ __forceinline__ bf16x8 ld_frag(const unsigned short* p) {
    union { uint4 u; bf16x8 v; } c;
    c.u = *reinterpret_cast<const uint4*>(p);
    return c.v;
}

// async global->LDS, 16B per lane; LDS dest is wave-uniform base + lane*16
__device__ __forceinline__ void gload_lds16(const unsigned short* g, unsigned short* l) {
    __builtin_amdgcn_global_load_lds(
        (const __attribute__((address_space(1))) unsigned int*)g,
        (__attribute__((address_space(3))) unsigned int*)l, 16, 0, 0);
}

// ---------------- merged cast fp32 -> bf16 (all 4 weight mats, float4-vectorized) ----------------
__global__ __launch_bounds__(256) void cast4_kernel(const float* __restrict__ qkvw,
                                                    const float* __restrict__ projw,
                                                    const float* __restrict__ fc1w,
                                                    const float* __restrict__ fc2w,
                                                    unsigned short* __restrict__ dq,
                                                    unsigned short* __restrict__ dp,
                                                    unsigned short* __restrict__ d1,
                                                    unsigned short* __restrict__ d2) {
    int i = blockIdx.x * 256 + threadIdx.x;     // vec4 index; total 1,769,472
    const int N0 = 442368, N1 = 147456, N2 = 589824;
    const float* s; unsigned short* d; int j;
    if (i < N0)                { s = qkvw; d = dq; j = i; }
    else if (i < N0 + N1)      { s = projw; d = dp; j = i - N0; }
    else if (i < N0 + N1 + N2) { s = fc1w;  d = d1; j = i - N0 - N1; }
    else                       { s = fc2w;  d = d2; j = i - N0 - N1 - N2; }
    float4 v = reinterpret_cast<const float4*>(s)[j];
    union { unsigned short us[4]; uint2 u; } o;
    o.us[0] = f2bf(v.x); o.us[1] = f2bf(v.y); o.us[2] = f2bf(v.z); o.us[3] = f2bf(v.w);
    reinterpret_cast<uint2*>(d)[j] = o.u;
}

// ---------------- prune: token mask ----------------
__global__ __launch_bounds__(256) void prune_kernel(const float* __restrict__ scores,
                                                    float* __restrict__ maskf,
                                                    float* __restrict__ cnt) {
    int b = blockIdx.x, tid = threadIdx.x;
    int lane = tid & 63, wave = tid >> 6;
    __shared__ float ps[576];
    __shared__ float red[4];
    for (int j = tid; j < 576; j += 256) ps[j] = 0.f;
    __syncthreads();
    for (int l = 0; l < L_; ++l) {
        const float* row = scores + ((size_t)b * L_ + l) * N_ + 1;
        float mx = -3.4e38f;
        for (int j = tid; j < 576; j += 256) mx = fmaxf(mx, row[j]);
        for (int off = 32; off; off >>= 1) mx = fmaxf(mx, __shfl_xor(mx, off));
        if (lane == 0) red[wave] = mx;
        __syncthreads();
        mx = fmaxf(fmaxf(red[0], red[1]), fmaxf(red[2], red[3]));
        __syncthreads();
        float s = 0.f;
        for (int j = tid; j < 576; j += 256) s += expf(row[j] - mx);
        for (int off = 32; off; off >>= 1) s += __shfl_xor(s, off);
        if (lane == 0) red[wave] = s;
        __syncthreads();
        s = red[0] + red[1] + red[2] + red[3];
        float inv = 1.f / s;
        for (int j = tid; j < 576; j += 256) ps[j] += expf(row[j] - mx) * inv;
        __syncthreads();
    }
    for (int j = tid; j < 576; j += 256) ps[j] = ps[j] / 11.0f;
    __syncthreads();
    int kept = 0;
    for (int i = tid; i < 576; i += 256) {
        float vi = ps[i];
        float s = 0.f;
        for (int j = 0; j < 576; ++j) {
            float vj = ps[j];
            if (vj < vi || (vj == vi && j <= i)) s += vj;
        }
        int k = (s > 0.5f) ? 1 : 0;
        maskf[b * N_ + 1 + i] = (float)k;
        kept += k;
    }
    __syncthreads();
    for (int off = 32; off; off >>= 1) kept += __shfl_xor(kept, off);
    if (lane == 0) red[wave] = (float)kept;
    __syncthreads();
    if (tid == 0) {
        cnt[b] = red[0] + red[1] + red[2] + red[3] + 1.f;  // +CLS
        maskf[b * N_] = 1.f;
    }
}

// ---------------- layer norm (row-wise): optional bf16 out, optional stats ----------------
template<typename T>
__global__ __launch_bounds__(256) void ln_kernel(const T* __restrict__ x,
                                                 const float* __restrict__ g,
                                                 const float* __restrict__ bta,
                                                 unsigned short* __restrict__ dst_bf,
                                                 float* __restrict__ mu_out,
                                                 float* __restrict__ rs_out) {
    int row = blockIdx.x, tid = threadIdx.x;
    int lane = tid & 63, wave = tid >> 6;
    const T* xr = x + (size_t)row * C_;
    __shared__ float s1[4], s2[4];
    float s = 0.f, sq = 0.f;
    for (int c = tid; c < C_; c += 256) { float v = ldval(xr, c); s += v; sq += v * v; }
    for (int off = 32; off; off >>= 1) { s += __shfl_xor(s, off); sq += __shfl_xor(sq, off); }
    if (lane == 0) { s1[wave] = s; s2[wave] = sq; }
    __syncthreads();
    float ts = s1[0] + s1[1] + s1[2] + s1[3];
    float tq = s2[0] + s2[1] + s2[2] + s2[3];
    float mean = ts / (float)C_;
    float var = tq / (float)C_ - mean * mean;
    float rs = rsqrtf(var + 1e-6f);
    if (mu_out && tid == 0) { mu_out[row] = mean; rs_out[row] = rs; }
    if (dst_bf) {
        for (int c = tid; c < C_; c += 256) {
            float v = (ldval(xr, c) - mean) * rs * g[c] + bta[c];
            dst_bf[(size_t)row * C_ + c] = f2bf(v);
        }
    }
}

// ---------------- GEMM (m97 structure, BK=64): C[m,n] = sum_k A[m,k]*B[n,k], bf16 in --------
template<int MODE, int MI>
__global__ __launch_bounds__(256) void gemm_kernel(const unsigned short* __restrict__ A,
                                                   const unsigned short* __restrict__ Bm,
                                                   const float* __restrict__ bias,
                                                   const float* __restrict__ residf,
                                                   const unsigned short* __restrict__ residb,
                                                   unsigned short* __restrict__ outb,
                                                   unsigned short* __restrict__ qd,
                                                   unsigned short* __restrict__ kd,
                                                   unsigned short* __restrict__ vd,
                                                   int M, int N, int K) {
    constexpr int TILE = MI * 32;
    __shared__ unsigned short As[2][TILE * 32];   // two 32-k chunks per barrier round
    __shared__ unsigned short Bs[2][TILE * 32];
    int bid = blockIdx.x;
    int NT = N / TILE;
    int mt = bid / NT, nt = bid % NT;
    int m0 = mt * TILE, n0 = nt * TILE;
    int tid = threadIdx.x, lane = tid & 63, wave = tid >> 6;
    int ml = lane & 15, quad = lane >> 4;
    int srow = wave * 16 + (lane >> 2);
    int skc = (lane & 3) * 8;
    const unsigned short* ag[MI / 2 == 0 ? 1 : MI / 2];
    const unsigned short* bg[MI / 2 == 0 ? 1 : MI / 2];
#pragma unroll
    for (int jj = 0; jj < MI / 2; ++jj) {
        ag[jj] = A + (size_t)min(m0 + jj * 64 + srow, M - 1) * K + skc;
        bg[jj] = Bm + (size_t)(n0 + jj * 64 + srow) * K + skc;
    }
    int msub = (wave & 1) * (MI * 16), nsub = (wave >> 1) * (MI * 16);
    f32x4 acc[MI][MI] = {};
    for (int k0 = 0; k0 < K; k0 += 64) {
        __syncthreads();
#pragma unroll
        for (int c = 0; c < 2; ++c)
#pragma unroll
        for (int jj = 0; jj < MI / 2; ++jj) {
            gload_lds16(ag[jj] + k0 + c * 32, As[c] + jj * 2048 + wave * 512);
            gload_lds16(bg[jj] + k0 + c * 32, Bs[c] + jj * 2048 + wave * 512);
        }
        asm volatile("s_waitcnt vmcnt(0)" ::: "memory");
        __syncthreads();
#pragma unroll
        for (int c = 0; c < 2; ++c) {
            bf16x8 af[MI], bfm[MI];
#pragma unroll
            for (int i = 0; i < MI; ++i) af[i] = ld_frag(As[c] + (msub + 16 * i + ml) * 32 + quad * 8);
#pragma unroll
            for (int j = 0; j < MI; ++j) bfm[j] = ld_frag(Bs[c] + (nsub + 16 * j + ml) * 32 + quad * 8);
#pragma unroll
            for (int i = 0; i < MI; ++i)
#pragma unroll
                for (int j = 0; j < MI; ++j)
                    acc[i][j] = __builtin_amdgcn_mfma_f32_16x16x32_bf16(af[i], bfm[j], acc[i][j], 0, 0, 0);
        }
    }
#pragma unroll
    for (int i = 0; i < MI; ++i)
#pragma unroll
    for (int j = 0; j < MI; ++j)
#pragma unroll
    for (int r = 0; r < 4; ++r) {
        int row = m0 + msub + 16 * i + quad * 4 + r;
        if (row >= M) continue;
        int col = n0 + nsub + 16 * j + ml;
        float v = acc[i][j][r] + bias[col];
        if (MODE == 0) {
            int b = row / N_, t = row - b * N_;
            int f = col;
            if (f < 768) {
                qd[((size_t)(b * H_ + (f >> 6)) * N_ + t) * HD_ + (f & 63)] = f2bf(v * 0.125f);
            } else if (f < 1536) {
                f -= 768;
                kd[((size_t)(b * H_ + (f >> 6)) * N_ + t) * HD_ + (f & 63)] = f2bf(v);
            } else {
                f -= 1536;
                vd[((size_t)(b * H_ + (f >> 6)) * HD_ + (f & 63)) * NP_ + t] = f2bf(v);
            }
        } else if (MODE == 1) {
            outb[(size_t)row * N + col] = f2bf(v + residf[(size_t)row * N + col]);
        } else if (MODE == 2) {
            float gl = 0.5f * v * (1.f + erff(v * 0.70710678118654752f));
            outb[(size_t)row * N + col] = f2bf(gl);
        } else {
            outb[(size_t)row * N + col] = f2bf(v + bf2f(residb[(size_t)row * N + col]));
        }
    }
}

// ---------------- fused masked attention: 32-row q tile, 1 barrier ----------------
// No max-subtraction (|S|<~5: LN'd inputs x 0.02-scaled weights -> exp safe). P stored as raw
// exp; 1/sum + q-row mask applied on the O accumulator. Each block amortizes its (b,h) K/V
// read over 32 q rows. Swizzle keeps each (b,h)'s K/V in one XCD's L2.
__global__ __launch_bounds__(256, 4) void attn_kernel(const unsigned short* __restrict__ qb,
                                                      const unsigned short* __restrict__ kb,
                                                      const unsigned short* __restrict__ vt,
                                                      const float* __restrict__ maskf,
                                                      unsigned short* __restrict__ ybf) {
    int bid = blockIdx.x;
    int xcd = bid & 7, g = bid >> 3;
    int bh = (g / NQT_) * 8 + xcd;
    int qt = g % NQT_;
    int h = bh % H_, b = bh / H_;
    int q0 = qt * QT_;
    int tid = threadIdx.x, lane = tid & 63, wave = tid >> 6;
    int ml = lane & 15, quad = lane >> 4, kq = quad * 8;
    __shared__ __align__(16) unsigned short P[QT_][616];   // 39.4 KB
    __shared__ float wred[4][QT_];

    const float* bmask = maskf + (size_t)b * N_;
    float mrowv[2][4];
#pragma unroll
    for (int s = 0; s < 2; ++s)
#pragma unroll
    for (int r = 0; r < 4; ++r) {
        int t = q0 + s * 16 + quad * 4 + r;
        mrowv[s][r] = (t < N_) ? bmask[t] : 0.f;
    }
    // phase 1: S in registers -> exp inline -> P (raw, unscaled) + per-row partial sums
    const unsigned short* qbase = qb + (size_t)(b * H_ + h) * N_ * HD_;
    const unsigned short* kbase = kb + (size_t)(b * H_ + h) * N_ * HD_;
    bf16x8 aq[2][2];
#pragma unroll
    for (int s = 0; s < 2; ++s) {
        int qrow = min(q0 + s * 16 + ml, N_ - 1);
        aq[s][0] = ld_frag(qbase + (size_t)qrow * HD_ + kq);
        aq[s][1] = ld_frag(qbase + (size_t)qrow * HD_ + kq + 32);
    }
    float ls[2][4] = {};
#pragma unroll
    for (int t = 0; t < 10; ++t) {
        int nt = wave + 4 * t;
        if (nt < NP_ / 16) {
            int col = nt * 16 + ml;
            int krow = min(col, N_ - 1);
            bf16x8 bk0 = ld_frag(kbase + (size_t)krow * HD_ + kq);
            bf16x8 bk1 = ld_frag(kbase + (size_t)krow * HD_ + kq + 32);
            bool keep = (col < N_) && (bmask[col] > 0.f);
#pragma unroll
            for (int s = 0; s < 2; ++s) {
                f32x4 a = {0.f, 0.f, 0.f, 0.f};
                a = __builtin_amdgcn_mfma_f32_16x16x32_bf16(aq[s][0], bk0, a, 0, 0, 0);
                a = __builtin_amdgcn_mfma_f32_16x16x32_bf16(aq[s][1], bk1, a, 0, 0, 0);
#pragma unroll
                for (int r = 0; r < 4; ++r) {
                    float e = keep ? __expf(a[r]) : 0.f;
                    ls[s][r] += e;
                    P[s * 16 + quad * 4 + r][col] = f2bf(e);
                }
            }
        }
    }
#pragma unroll
    for (int s = 0; s < 2; ++s)
#pragma unroll
    for (int r = 0; r < 4; ++r) {
#pragma unroll
        for (int off = 1; off < 16; off <<= 1) ls[s][r] += __shfl_xor(ls[s][r], off);
    }
    if (ml == 0) {
#pragma unroll
        for (int s = 0; s < 2; ++s)
#pragma unroll
        for (int r = 0; r < 4; ++r) wred[wave][s * 16 + quad * 4 + r] = ls[s][r];
    }
    __syncthreads();   // the ONLY barrier
    float inv[2][4];
#pragma unroll
    for (int s = 0; s < 2; ++s)
#pragma unroll
    for (int r = 0; r < 4; ++r) {
        int row = s * 16 + quad * 4 + r;
        float sum = wred[0][row] + wred[1][row] + wred[2][row] + wred[3][row];
        inv[s][r] = mrowv[s][r] / sum;   // masked q-rows -> 0 (CLS key always kept => sum>0)
    }
    // phase 3: O = P @ V; one V fragment serves both 16-row q sub-tiles
    const unsigned short* vrow = vt + ((size_t)(b * H_ + h) * HD_ + wave * 16 + ml) * NP_ + kq;
    f32x4 acc[2] = {};
#pragma unroll
    for (int t = 0; t < 19; ++t) {
        bf16x8 vb = ld_frag(vrow + t * 32);
#pragma unroll
        for (int s = 0; s < 2; ++s) {
            bf16x8 pa = ld_frag(&P[s * 16 + ml][kq + t * 32]);
            acc[s] = __builtin_amdgcn_mfma_f32_16x16x32_bf16(pa, vb, acc[s], 0, 0, 0);
        }
    }
#pragma unroll
    for (int s = 0; s < 2; ++s)
#pragma unroll
    for (int r = 0; r < 4; ++r) {
        int t = q0 + s * 16 + quad * 4 + r;
        if (t < N_)
            ybf[((size_t)(b * N_ + t)) * C_ + h * HD_ + wave * 16 + ml] = f2bf(acc[s][r] * inv[s][r]);
    }
}

// ---------------- masked pooled raw sums of bbn-normalized x2 ----------------
__global__ __launch_bounds__(256) void pool_kernel(const unsigned short* __restrict__ x2,
                                                   const float* __restrict__ mu,
                                                   const float* __restrict__ rs,
                                                   const float* __restrict__ maskf,
                                                   float* __restrict__ praw) {
    int c = blockIdx.x * 256 + threadIdx.x;
    int tchunk = blockIdx.y;
    int b = blockIdx.z;
    int t0 = tchunk * 73, t1 = min(t0 + 73, N_);
    float s = 0.f;
    for (int t = t0; t < t1; ++t) {
        int row = b * N_ + t;
        float m = maskf[row];
        if (m > 0.f) s += (bf2f(x2[(size_t)row * C_ + c]) - mu[row]) * rs[row];
    }
    atomicAdd(&praw[b * C_ + c], s);
}

// ---------------- finish: bbn affine + /cnt, then final LN -> out ----------------
__global__ __launch_bounds__(256) void final_kernel(const float* __restrict__ praw,
                                                    const float* __restrict__ cnt,
                                                    const float* __restrict__ bg,
                                                    const float* __restrict__ bb,
                                                    const float* __restrict__ og,
                                                    const float* __restrict__ ob,
                                                    float* __restrict__ out) {
    int b = blockIdx.x, tid = threadIdx.x;
    int lane = tid & 63, wave = tid >> 6;
    __shared__ float u[C_];
    __shared__ float r1[4], r2[4];
    float inv = 1.f / cnt[b];
    float s = 0.f, sq = 0.f;
    for (int c = tid; c < C_; c += 256) {
        float v = bg[c] * praw[b * C_ + c] * inv + bb[c];
        u[c] = v; s += v; sq += v * v;
    }
    for (int off = 32; off; off >>= 1) { s += __shfl_xor(s, off); sq += __shfl_xor(sq, off); }
    if (lane == 0) { r1[wave] = s; r2[wave] = sq; }
    __syncthreads();
    float ts = r1[0] + r1[1] + r1[2] + r1[3];
    float tq = r2[0] + r2[1] + r2[2] + r2[3];
    float mean = ts / (float)C_;
    float var = tq / (float)C_ - mean * mean;
    float rstd = rsqrtf(var + 1e-6f);
    for (int c = tid; c < C_; c += 256)
        out[b * C_ + c] = (u[c] - mean) * rstd * og[c] + ob[c];
}

extern "C" void kernel_launch(void* const* d_in, const int* in_sizes, int n_in,
                              void* d_out, int out_size, void* d_ws, size_t ws_size,
                              hipStream_t stream) {
    const float* last_x  = (const float*)d_in[0];
    const float* scores  = (const float*)d_in[1];
    const float* n1g     = (const float*)d_in[2];
    const float* n1b     = (const float*)d_in[3];
    const float* qkv_w   = (const float*)d_in[4];
    const float* qkv_b   = (const float*)d_in[5];
    const float* proj_w  = (const float*)d_in[6];
    const float* proj_b  = (const float*)d_in[7];
    const float* n2g     = (const float*)d_in[8];
    const float* n2b     = (const float*)d_in[9];
    const float* fc1_w   = (const float*)d_in[10];
    const float* fc1_b   = (const float*)d_in[11];
    const float* fc2_w   = (const float*)d_in[12];
    const float* fc2_b   = (const float*)d_in[13];
    const float* bbn_g   = (const float*)d_in[14];
    const float* bbn_b   = (const float*)d_in[15];
    const float* out_g   = (const float*)d_in[16];
    const float* out_b   = (const float*)d_in[17];
    float* out = (float*)d_out;

    char* w = (char*)d_ws;
    size_t off = 0;
    auto alloc = [&](size_t bytes) -> char* {
        off = (off + 255) & ~(size_t)255;
        char* p = w + off;
        off += bytes;
        return p;
    };
    unsigned short* wq = (unsigned short*)alloc((size_t)2304 * 768 * 2);
    unsigned short* wp = (unsigned short*)alloc((size_t)768 * 768 * 2);
    unsigned short* w1 = (unsigned short*)alloc((size_t)3072 * 768 * 2);
    unsigned short* w2 = (unsigned short*)alloc((size_t)768 * 3072 * 2);
    float* maskf = (float*)alloc((size_t)M_ * 4);
    float* cnt   = (float*)alloc(32 * 4);
    float* mu    = (float*)alloc((size_t)M_ * 4);
    float* rs    = (float*)alloc((size_t)M_ * 4);
    float* praw  = (float*)alloc((size_t)B_ * C_ * 4);
    unsigned short* h_bf = (unsigned short*)alloc((size_t)M_ * C_ * 2);            // h -> y -> act(fallback)
    unsigned short* q_bf = (unsigned short*)alloc((size_t)B_ * H_ * N_ * HD_ * 2); // q -> m (LN2 out)
    unsigned short* k_bf = (unsigned short*)alloc((size_t)B_ * H_ * N_ * HD_ * 2); // k -> x2 (bf16)
    unsigned short* vt   = (unsigned short*)alloc((size_t)B_ * H_ * HD_ * NP_ * 2); // vt -> x1 (bf16)
    unsigned short* y_bf = h_bf;
    unsigned short* m_bf = q_bf;
    unsigned short* x1   = vt;
    unsigned short* x2   = k_bf;

    size_t act_need = (size_t)M_ * 3072 * 2;
    bool big = (((off + 255) & ~(size_t)255) + act_need) <= ws_size;
    unsigned short* act = big ? (unsigned short*)alloc(act_need) : h_bf;

    // 1. cast weights to bf16 (single merged launch)
    cast4_kernel<<<6912, 256, 0, stream>>>(qkv_w, proj_w, fc1_w, fc2_w, wq, wp, w1, w2);
    // 2. prune mask
    prune_kernel<<<B_, 256, 0, stream>>>(scores, maskf, cnt);
    // 3. LN1 -> h (bf16)
    ln_kernel<float><<<M_, 256, 0, stream>>>(last_x, n1g, n1b, h_bf, nullptr, nullptr);
    // 4. QKV gemm (128-tile), split store
    gemm_kernel<0, 4><<<((M_ + 127) / 128) * (2304 / 128), 256, 0, stream>>>(
        h_bf, wq, qkv_b, nullptr, nullptr, nullptr, q_bf, k_bf, vt, M_, 2304, C_);
    // 5. masked attention -> y
    attn_kernel<<<B_ * H_ * NQT_, 256, 0, stream>>>(q_bf, k_bf, vt, maskf, y_bf);
    // 6. proj gemm + residual(f32 last_x) -> x1 (bf16)
    gemm_kernel<1, 4><<<((M_ + 127) / 128) * (768 / 128), 256, 0, stream>>>(
        y_bf, wp, proj_b, last_x, nullptr, x1, nullptr, nullptr, nullptr, M_, C_, C_);
    // 7. LN2 -> m (bf16)
    ln_kernel<unsigned short><<<M_, 256, 0, stream>>>(x1, n2g, n2b, m_bf, nullptr, nullptr);
    // 8/9. MLP: unchunked 128-tile if workspace allows, else 4 chunks at 128-tile
    if (big) {
        gemm_kernel<2, 4><<<((M_ + 127) / 128) * (3072 / 128), 256, 0, stream>>>(
            m_bf, w1, fc1_b, nullptr, nullptr, act, nullptr, nullptr, nullptr, M_, 3072, C_);
        gemm_kernel<3, 4><<<((M_ + 127) / 128) * (768 / 128), 256, 0, stream>>>(
            act, w2, fc2_b, nullptr, x1, x2, nullptr, nullptr, nullptr, M_, C_, 3072);
    } else {
        for (int c = 0; c < 4; ++c) {
            int r0 = c * MCH_;
            gemm_kernel<2, 4><<<((MCH_ + 127) / 128) * (3072 / 128), 256, 0, stream>>>(
                m_bf + (size_t)r0 * C_, w1, fc1_b, nullptr, nullptr, act,
                nullptr, nullptr, nullptr, MCH_, 3072, C_);
            gemm_kernel<3, 4><<<((MCH_ + 127) / 128) * (768 / 128), 256, 0, stream>>>(
                act, w2, fc2_b, nullptr, x1 + (size_t)r0 * C_, x2 + (size_t)r0 * C_,
                nullptr, nullptr, nullptr, MCH_, 768, 3072);
        }
    }
    // 10. bbn LN stats only
    ln_kernel<unsigned short><<<M_, 256, 0, stream>>>(x2, bbn_g, bbn_b, nullptr, mu, rs);
    // 11. masked pooled raw sums
    hipMemsetAsync(praw, 0, (size_t)B_ * C_ * 4, stream);
    dim3 pg(3, 8, B_);
    pool_kernel<<<pg, 256, 0, stream>>>(x2, mu, rs, maskf, praw);
    // 12. bbn affine + /cnt + final LN -> out
    final_kernel<<<B_, 256, 0, stream>>>(praw, cnt, bbn_g, bbn_b, out_g, out_b, out);
    (void)in_sizes; (void)n_in; (void)out_size;
}